// Round 6
// baseline (863.074 us; speedup 1.0000x reference)
//
#include <hip/hip_runtime.h>

typedef unsigned short u16;
typedef __bf16 bf16x8 __attribute__((ext_vector_type(8)));
typedef float f32x4 __attribute__((ext_vector_type(4)));

static __device__ __forceinline__ f32x4 mfma16(bf16x8 a, bf16x8 b, f32x4 c) {
  return __builtin_amdgcn_mfma_f32_16x16x32_bf16(a, b, c, 0, 0, 0);
}

static __device__ __forceinline__ u16 f2bf(float f) {
  union { float f; unsigned u; } v; v.f = f;
  unsigned r = v.u + 0x7fffu + ((v.u >> 16) & 1u);
  return (u16)(r >> 16);
}

// async global->LDS DMA, 16B per lane; dest = wave-uniform base + lane*16
static __device__ __forceinline__ void gl2lds16(const u16* g, u16* l) {
  __builtin_amdgcn_global_load_lds(
      (const __attribute__((address_space(1))) unsigned int*)g,
      (__attribute__((address_space(3))) unsigned int*)l, 16, 0, 0);
}

// ---------------- mask element-size probe ----------------
__global__ void k_flag(const unsigned char* __restrict__ m, int* flag) {
  int t = threadIdx.x;  // 64 threads
  unsigned v = (unsigned)m[4*t+1] | (unsigned)m[4*t+2] | (unsigned)m[4*t+3];
  unsigned long long any = __ballot(v != 0);
  if (t == 0) *flag = (any == 0ull) ? 1 : 0;
}

// ---------------- mask bit-pack: elem -> 1 bit ----------------
__global__ __launch_bounds__(256) void k_pack(const void* __restrict__ m,
                                              const int* __restrict__ flagp,
                                              unsigned* __restrict__ out) {
  int flag = *flagp;
  int lane = threadIdx.x & 63, wv = threadIdx.x >> 6;
  long base = (long)blockIdx.x * 2048 + wv * 64 + lane;
#pragma unroll
  for (int it = 0; it < 8; ++it) {
    long elem = base + it * 256;
    bool pred = flag ? (((const int*)m)[elem] != 0)
                     : (((const unsigned char*)m)[elem] != 0);
    unsigned long long bal = __ballot(pred);
    if (lane == 0)  out[elem >> 5] = (unsigned)bal;
    if (lane == 32) out[elem >> 5] = (unsigned)(bal >> 32);
  }
}

// ---------------- weight composition: Weff = W0*W1*W2 (fp32), beff likewise ----------
static __device__ __forceinline__ const float* wbase(int p, const float* Wq,
                                                     const float* Wk, const float* Wv) {
  return (p < 4) ? (Wq + (size_t)p * 196608)
       : (p < 8) ? (Wk + (size_t)(p - 4) * 196608)
                 : (Wv + (size_t)(p - 8) * 196608);
}

// T[p][r][c] = sum_d W0[r][d] * W1[d][c]   (fp32)
__global__ __launch_bounds__(256) void k_wc1(const float* __restrict__ Wq,
                                             const float* __restrict__ Wk,
                                             const float* __restrict__ Wv,
                                             float* __restrict__ T) {
  int p = blockIdx.y, r = blockIdx.x, c = threadIdx.x;
  const float* W0 = wbase(p, Wq, Wk, Wv);
  const float* W1 = W0 + 65536;
  const float* w0r = W0 + (size_t)r * 256;
  float a0 = 0.f, a1 = 0.f, a2 = 0.f, a3 = 0.f;
  for (int d = 0; d < 256; d += 4) {
    a0 += w0r[d]     * W1[(size_t)d * 256 + c];
    a1 += w0r[d + 1] * W1[(size_t)(d + 1) * 256 + c];
    a2 += w0r[d + 2] * W1[(size_t)(d + 2) * 256 + c];
    a3 += w0r[d + 3] * W1[(size_t)(d + 3) * 256 + c];
  }
  T[((size_t)p * 256 + r) * 256 + c] = (a0 + a1) + (a2 + a3);
}

// Wt[p][e][d] = bf16( sum_c T[p][d][c] * W2[c][e] )   (transposed-out for the GEMM)
__global__ __launch_bounds__(256) void k_wc2(const float* __restrict__ Wq,
                                             const float* __restrict__ Wk,
                                             const float* __restrict__ Wv,
                                             const float* __restrict__ T,
                                             u16* __restrict__ Wt) {
  int p = blockIdx.y, e0 = blockIdx.x << 4, d = threadIdx.x;
  const float* W2 = wbase(p, Wq, Wk, Wv) + 131072;
  __shared__ __align__(16) float sw[256][16];
#pragma unroll
  for (int j = 0; j < 4; ++j)
    *(float4*)&sw[d][j * 4] = *(const float4*)&W2[(size_t)d * 256 + e0 + j * 4];
  __syncthreads();
  const float* Tr = T + ((size_t)p * 256 + d) * 256;
  float acc[16];
#pragma unroll
  for (int j = 0; j < 16; ++j) acc[j] = 0.f;
  for (int c = 0; c < 256; c += 4) {
    float4 tv = *(const float4*)&Tr[c];
#pragma unroll
    for (int j = 0; j < 16; ++j) {
      acc[j] += tv.x * sw[c][j];
      acc[j] += tv.y * sw[c + 1][j];
      acc[j] += tv.z * sw[c + 2][j];
      acc[j] += tv.w * sw[c + 3][j];
    }
  }
#pragma unroll
  for (int j = 0; j < 16; ++j)
    Wt[((size_t)p * 256 + e0 + j) * 256 + d] = f2bf(acc[j]);
}

// beff[p][e] = ((b0*W1 + b1)*W2 + b2)[e]
__global__ __launch_bounds__(256) void k_bc(const float* __restrict__ Wq,
                                            const float* __restrict__ Wk,
                                            const float* __restrict__ Wv,
                                            const float* __restrict__ bq,
                                            const float* __restrict__ bk,
                                            const float* __restrict__ bv,
                                            float* __restrict__ beff) {
  int p = blockIdx.x, t = threadIdx.x;
  const float* W0 = wbase(p, Wq, Wk, Wv);
  const float* W1 = W0 + 65536;
  const float* W2 = W0 + 131072;
  const float* b = (p < 4) ? (bq + p * 768)
                 : (p < 8) ? (bk + (p - 4) * 768)
                           : (bv + (p - 8) * 768);
  __shared__ float s1[256];
  float a = 0.f;
  for (int d = 0; d < 256; ++d) a += b[d] * W1[(size_t)d * 256 + t];
  s1[t] = a + b[256 + t];
  __syncthreads();
  float a2 = 0.f;
  for (int c = 0; c < 256; ++c) a2 += s1[c] * W2[(size_t)c * 256 + t];
  beff[p * 256 + t] = a2 + b[512 + t];
}

// ---------------- fp32 -> bf16 convert ----------------
__global__ __launch_bounds__(256) void k_cvt(const float* __restrict__ src,
                                             u16* __restrict__ db, long n) {
  long i = ((long)blockIdx.x * 256 + threadIdx.x) * 4;
  if (i >= n) return;
  float4 v = *(const float4*)(src + i);
  union { u16 u[4]; uint2 q; } o;
  o.u[0] = f2bf(v.x); o.u[1] = f2bf(v.y); o.u[2] = f2bf(v.z); o.u[3] = f2bf(v.w);
  *(uint2*)(db + i) = o.q;
}

// ---------------- projection: W-in-registers, X DMA dbuf, 1 barrier/tile ----------------
// Block = 256 thr (4 waves). Wave w owns output cols [w*64, w*64+64). Whole 256x256
// bf16 W held in registers (wf[8][4] = 128 VGPR/lane). Grid-strides 2 row-tiles of 64;
// X staged via global_load_lds (pre-swizzled source, linear LDS, swizzled read),
// double-buffered; one vmcnt(0)+barrier per tile.
template<int MODE>
static __device__ __forceinline__ void proj_body(
    const u16* __restrict__ X, const u16* __restrict__ Wg,
    const float* __restrict__ bias, u16* __restrict__ out, int Nk,
    int t0, int nt, u16 (*Xs)[64][256]) {
  int t = threadIdx.x, lane = t & 63, w = t >> 6, g = lane >> 4, li = lane & 15;
  int rbase = (w << 1) | (lane >> 5);            // 0..7
  int scg = (lane & 31) ^ rbase;                 // pre-swizzled source col-group

  // preload full W into registers
  bf16x8 wf[8][4];
#pragma unroll
  for (int kk = 0; kk < 8; ++kk)
#pragma unroll
    for (int f = 0; f < 4; ++f)
      wf[kk][f] = *(const bf16x8*)&Wg[(size_t)(w * 64 + f * 16 + li) * 256 + kk * 32 + g * 8];

  // stage tile t0 -> buf0
  {
    const u16* sb = X + ((long)t0 * 64 + rbase) * 256 + (scg << 3);
    u16* db = &Xs[0][0][0] + (w << 9);
#pragma unroll
    for (int r8 = 0; r8 < 8; ++r8) gl2lds16(sb + r8 * 2048, db + r8 * 2048);
  }
  asm volatile("s_waitcnt vmcnt(0)" ::: "memory");
  __syncthreads();

  for (int ti = 0; ti < nt; ++ti) {
    int p = ti & 1;
    if (ti + 1 < nt) {   // DMA next tile into the other buffer
      const u16* sb = X + ((long)(t0 + ti + 1) * 64 + rbase) * 256 + (scg << 3);
      u16* db = &Xs[p ^ 1][0][0] + (w << 9);
#pragma unroll
      for (int r8 = 0; r8 < 8; ++r8) gl2lds16(sb + r8 * 2048, db + r8 * 2048);
    }
    f32x4 acc[4][4];
#pragma unroll
    for (int i = 0; i < 4; ++i)
#pragma unroll
      for (int jj = 0; jj < 4; ++jj) acc[i][jj] = (f32x4){0.f, 0.f, 0.f, 0.f};
#pragma unroll
    for (int kk = 0; kk < 8; ++kk) {
      bf16x8 xf[4];
#pragma unroll
      for (int f = 0; f < 4; ++f)
        xf[f] = *(const bf16x8*)&Xs[p][f * 16 + li][((kk * 4 + g) ^ (li & 7)) << 3];
#pragma unroll
      for (int i = 0; i < 4; ++i)
#pragma unroll
        for (int jj = 0; jj < 4; ++jj)
          acc[i][jj] = (MODE == 0) ? mfma16(xf[i], wf[kk][jj], acc[i][jj])
                                   : mfma16(wf[kk][i], xf[jj], acc[i][jj]);
    }
    asm volatile("s_waitcnt vmcnt(0)" ::: "memory");
    __syncthreads();
    long row0 = (long)(t0 + ti) * 64;
    if (MODE == 0) {
#pragma unroll
      for (int i = 0; i < 4; ++i)
#pragma unroll
        for (int jj = 0; jj < 4; ++jj)
#pragma unroll
          for (int r = 0; r < 4; ++r) {
            int R = i * 16 + g * 4 + r, C = w * 64 + jj * 16 + li;
            out[(row0 + R) * 256 + C] = f2bf(acc[i][jj][r] + bias[C]);
          }
    } else {
      long b = row0 / Nk, rb = row0 - b * Nk;
#pragma unroll
      for (int i = 0; i < 4; ++i)
#pragma unroll
        for (int jj = 0; jj < 4; ++jj)
#pragma unroll
          for (int r = 0; r < 4; ++r) {
            int e = w * 64 + i * 16 + g * 4 + r, xr = jj * 16 + li;
            out[(b * 256 + e) * (long)Nk + rb + xr] = f2bf(acc[i][jj][r] + bias[e]);
          }
    }
  }
}

// One dispatch per layer: Q blocks [0,128), K blocks [128,128+Mkv/2), V rest. 2 tiles/block.
__global__ __launch_bounds__(256, 2) void k_proj(
    const u16* __restrict__ Xq, const u16* __restrict__ Xkv,
    const u16* __restrict__ Wt, const float* __restrict__ beff,
    u16* __restrict__ Qb, u16* __restrict__ Kb, u16* __restrict__ Vt,
    int layer, int Mkv, int Nk) {
  __shared__ __align__(16) u16 Xs[2][64][256];
  int u = blockIdx.x, h = Mkv >> 1;
  if (u < 128)
    proj_body<0>(Xq, Wt + (size_t)layer * 65536, beff + layer * 256, Qb, 0,
                 u * 2, 2, Xs);
  else if (u < 128 + h)
    proj_body<0>(Xkv, Wt + (size_t)(4 + layer) * 65536, beff + (4 + layer) * 256, Kb, 0,
                 (u - 128) * 2, 2, Xs);
  else
    proj_body<1>(Xkv, Wt + (size_t)(8 + layer) * 65536, beff + (8 + layer) * 256, Vt, Nk,
                 (u - 128 - h) * 2, 2, Xs);
}

// ---------------- flash attention v6: single 64KB buffer, 2 blocks/CU ----------------
// Grid 256 x 512thr. Block = 64 q-rows, 8 waves: w -> (qt = w>>1, s = w&1).
// Per 64-k chunk: issue next chunk's global loads to regs (issue-early), compute
// QK (swapped, S[k][q] lane-local) -> exp -> register-shuffle P redistribution ->
// PV from XOR-swizzled LDS, barrier, write regs -> same buffer, barrier.
// LDS 65.3 KB -> 2 blocks/CU; cross-block overlap hides the barrier/latency chain.
__global__ __launch_bounds__(512, 2) void k_attn(
    const u16* __restrict__ Qb, const u16* __restrict__ Kb, const u16* __restrict__ Vt,
    const unsigned* __restrict__ Mb,
    const float* __restrict__ gamma, const float* __restrict__ beta,
    const float* __restrict__ rin, float* xres, u16* xbout,
    const float* __restrict__ future, float* __restrict__ dout, int last, int Nk) {
  __shared__ __align__(16) char RAW[66816];  // K 32KB | V 32KB; epilogue aliases all

  int t = threadIdx.x, lane = t & 63, w = t >> 6;
  int qt = w >> 1, s = w & 1;
  int g = lane >> 4, li = lane & 15;
  int sw = li & 7;

  // XCD-bijective swizzle: XCD x owns batches {2x, 2x+1} -> K/V stays in its L2.
  int n = blockIdx.x;
  int b = ((n & 7) << 1) | ((n >> 3) & 1);
  int q0 = (n >> 4) << 6;

  int W = Nk >> 5, nc = Nk >> 6;

  const u16* Kg = Kb + (long)b * Nk * 256;
  const u16* Vg = Vt + (long)b * 256 * (long)Nk;
  const unsigned* Mg = Mb + ((long)b * 1024 + q0 + qt * 16 + li) * W;
  const u16* Qg = Qb + ((long)b * 1024 + q0 + qt * 16 + li) * 256 + g * 8;

  // Per-thread staging slots (4 K + 4 V), swizzle on the GLOBAL source address:
  // K LDS[row][c] holds global (row, c^(row&7));  V LDS[d][c] holds global (d, c^(d&7)).
  int sA = t, sB = 512 + t, sC = 1024 + t, sD = 1536 + t;
  const u16* KgA = Kg + (long)(sA >> 5) * 256 + (((sA & 31) ^ ((sA >> 5) & 7)) << 3);
  const u16* KgB = Kg + (long)(sB >> 5) * 256 + (((sB & 31) ^ ((sB >> 5) & 7)) << 3);
  const u16* KgC = Kg + (long)(sC >> 5) * 256 + (((sC & 31) ^ ((sC >> 5) & 7)) << 3);
  const u16* KgD = Kg + (long)(sD >> 5) * 256 + (((sD & 31) ^ ((sD >> 5) & 7)) << 3);
  const u16* VgA = Vg + (long)(sA >> 3) * Nk + (((sA & 7) ^ ((sA >> 3) & 7)) << 3);
  const u16* VgB = Vg + (long)(sB >> 3) * Nk + (((sB & 7) ^ ((sB >> 3) & 7)) << 3);
  const u16* VgC = Vg + (long)(sC >> 3) * Nk + (((sC & 7) ^ ((sC >> 3) & 7)) << 3);
  const u16* VgD = Vg + (long)(sD >> 3) * Nk + (((sD & 7) ^ ((sD >> 3) & 7)) << 3);

  u16* Kw = (u16*)RAW;
  u16* Vw = Kw + 16384;

  // ---- prologue: chunk 0 -> regs, Q frags, chunk 0 -> buf, barrier ----
  uint4 k0 = *(const uint4*)KgA, k1 = *(const uint4*)KgB;
  uint4 k2 = *(const uint4*)KgC, k3 = *(const uint4*)KgD;
  uint4 v0 = *(const uint4*)VgA, v1 = *(const uint4*)VgB;
  uint4 v2 = *(const uint4*)VgC, v3 = *(const uint4*)VgD;
  bf16x8 qf[8];
#pragma unroll
  for (int kc = 0; kc < 8; ++kc) qf[kc] = *(const bf16x8*)(Qg + kc * 32);
  *(uint4*)&Kw[sA * 8] = k0; *(uint4*)&Kw[sB * 8] = k1;
  *(uint4*)&Kw[sC * 8] = k2; *(uint4*)&Kw[sD * 8] = k3;
  *(uint4*)&Vw[sA * 8] = v0; *(uint4*)&Vw[sB * 8] = v1;
  *(uint4*)&Vw[sC * 8] = v2; *(uint4*)&Vw[sD * 8] = v3;
  __syncthreads();

  f32x4 O[16];
#pragma unroll
  for (int dt = 0; dt < 16; ++dt) O[dt] = (f32x4){0.f, 0.f, 0.f, 0.f};
  float lsum = 0.f;

  for (int ci = 0; ci < nc; ++ci) {
    // issue next chunk's loads (clamped on last iter; branchless)
    long cb2 = (long)((ci + 1 < nc) ? ci + 1 : nc - 1) << 6;
    k0 = *(const uint4*)(KgA + cb2 * 256); k1 = *(const uint4*)(KgB + cb2 * 256);
    k2 = *(const uint4*)(KgC + cb2 * 256); k3 = *(const uint4*)(KgD + cb2 * 256);
    v0 = *(const uint4*)(VgA + cb2);       v1 = *(const uint4*)(VgB + cb2);
    v2 = *(const uint4*)(VgC + cb2);       v3 = *(const uint4*)(VgD + cb2);
    unsigned mw = Mg[(ci << 1) + s];

    const u16* Kr0 = Kw + (s * 32 + li) * 256;
    const u16* Kr1 = Kr0 + 4096;
    // QK^T swapped: st[t]: k = s*32 + t*16 + g*4 + r (within chunk), q = li
    f32x4 st0 = (f32x4){0.f, 0.f, 0.f, 0.f}, st1 = (f32x4){0.f, 0.f, 0.f, 0.f};
#pragma unroll
    for (int kc = 0; kc < 8; ++kc) {
      int co = ((kc * 4 + g) ^ sw) << 3;
      st0 = mfma16(*(const bf16x8*)&Kr0[co], qf[kc], st0);
      st1 = mfma16(*(const bf16x8*)&Kr1[co], qf[kc], st1);
    }
    float e0[4], e1[4];
#pragma unroll
    for (int r = 0; r < 4; ++r) {
      bool m0 = (mw >> (g * 4 + r)) & 1u;
      bool m1 = (mw >> (16 + g * 4 + r)) & 1u;
      e0[r] = m0 ? 0.f : __expf(st0[r] * 0.0625f);
      e1[r] = m1 ? 0.f : __expf(st1[r] * 0.0625f);
      lsum += e0[r] + e1[r];
    }
    unsigned u00 = (unsigned)f2bf(e0[0]) | ((unsigned)f2bf(e0[1]) << 16);
    unsigned u01 = (unsigned)f2bf(e0[2]) | ((unsigned)f2bf(e0[3]) << 16);
    unsigned u10 = (unsigned)f2bf(e1[0]) | ((unsigned)f2bf(e1[1]) << 16);
    unsigned u11 = (unsigned)f2bf(e1[2]) | ((unsigned)f2bf(e1[3]) << 16);
    int s0l = ((g & 1) << 5) + li;
    unsigned a0 = __shfl(u00, s0l),      a1 = __shfl(u01, s0l);
    unsigned a2 = __shfl(u00, s0l + 16), a3 = __shfl(u01, s0l + 16);
    unsigned c0 = __shfl(u10, s0l),      c1 = __shfl(u11, s0l);
    unsigned c2 = __shfl(u10, s0l + 16), c3 = __shfl(u11, s0l + 16);
    union { unsigned u[4]; bf16x8 v; } pa;
    bool hi = (g >= 2);
    pa.u[0] = hi ? c0 : a0; pa.u[1] = hi ? c1 : a1;
    pa.u[2] = hi ? c2 : a2; pa.u[3] = hi ? c3 : a3;
    // PV: O[q = g*4+r][d = dt*16+li], V^T rows from swizzled LDS
    const u16* Vr = Vw + li * 64 + (((s * 4 + g) ^ sw) << 3);
#pragma unroll
    for (int dt = 0; dt < 16; ++dt) {
      bf16x8 bv = *(const bf16x8*)&Vr[dt * 1024];
      O[dt] = mfma16(pa.v, bv, O[dt]);
    }
    __syncthreads();   // all reads of this chunk done
    if (ci + 1 < nc) { // write next chunk into the (single) buffer
      *(uint4*)&Kw[sA * 8] = k0; *(uint4*)&Kw[sB * 8] = k1;
      *(uint4*)&Kw[sC * 8] = k2; *(uint4*)&Kw[sD * 8] = k3;
      *(uint4*)&Vw[sA * 8] = v0; *(uint4*)&Vw[sB * 8] = v1;
      *(uint4*)&Vw[sC * 8] = v2; *(uint4*)&Vw[sD * 8] = v3;
      __syncthreads(); // staging visible
    }
  }

  // ---- epilogue: merge s-partials in LDS (aliases staging), LN, +residual ----
  float* Om = (float*)RAW;             // [4][16][260]
  float* Lm = (float*)(RAW + 66560);   // [4][16]
  lsum += __shfl_xor(lsum, 16);
  lsum += __shfl_xor(lsum, 32);        // all lanes: l[q=li] for this s-half
  if (s == 1) {
#pragma unroll
    for (int dt = 0; dt < 16; ++dt)
#pragma unroll
      for (int r = 0; r < 4; ++r)
        Om[(qt * 16 + g * 4 + r) * 260 + dt * 16 + li] = O[dt][r];
    if (g == 0) Lm[qt * 16 + li] = lsum;
  }
  __syncthreads();
  if (s == 0) {
    float rl = 1.f / fmaxf(lsum + Lm[qt * 16 + li], 1e-30f);
    float rq[4];
#pragma unroll
    for (int r = 0; r < 4; ++r) rq[r] = __shfl(rl, g * 4 + r);
    float sm[4] = {0.f, 0.f, 0.f, 0.f}, s2[4] = {0.f, 0.f, 0.f, 0.f};
#pragma unroll
    for (int dt = 0; dt < 16; ++dt)
#pragma unroll
      for (int r = 0; r < 4; ++r) {
        float y = (O[dt][r] + Om[(qt * 16 + g * 4 + r) * 260 + dt * 16 + li]) * rq[r];
        O[dt][r] = y;
        sm[r] += y; s2[r] += y * y;
      }
#pragma unroll
    for (int r = 0; r < 4; ++r) {
      float a = sm[r], c = s2[r];
      a += __shfl_xor(a, 1); a += __shfl_xor(a, 2);
      a += __shfl_xor(a, 4); a += __shfl_xor(a, 8);
      c += __shfl_xor(c, 1); c += __shfl_xor(c, 2);
      c += __shfl_xor(c, 4); c += __shfl_xor(c, 8);
      float m = a * (1.f / 256.f);
      sm[r] = m;
      s2[r] = rsqrtf(c * (1.f / 256.f) - m * m + 1e-5f);
    }
#pragma unroll
    for (int dt = 0; dt < 16; ++dt) {
      int d = dt * 16 + li;
      float gm = gamma[d], bt = beta[d];
#pragma unroll
      for (int r = 0; r < 4; ++r) {
        int q = q0 + qt * 16 + g * 4 + r;
        long idx = ((long)b * 1024 + q) * 256 + d;
        float o = (O[dt][r] - sm[r]) * s2[r] * gm + bt + rin[idx];
        if (last) dout[idx] = o + future[idx];
        else { xres[idx] = o; xbout[idx] = f2bf(o); }
      }
    }
  }
}

// ---------------- host ----------------
extern "C" void kernel_launch(void* const* d_in, const int* in_sizes, int n_in,
                              void* d_out, int out_size, void* d_ws, size_t ws_size,
                              hipStream_t stream) {
  const float* future  = (const float*)d_in[0];
  const float* history = (const float*)d_in[1];
  const float* graph   = (const float*)d_in[2];
  const void*  mask_hf = d_in[3];
  const void*  mask_fg = d_in[4];
  const float* Wq = (const float*)d_in[5];
  const float* bq = (const float*)d_in[6];
  const float* Wk = (const float*)d_in[7];
  const float* bk = (const float*)d_in[8];
  const float* Wv = (const float*)d_in[9];
  const float* bv = (const float*)d_in[10];
  const float* gamma = (const float*)d_in[11];
  const float* beta  = (const float*)d_in[12];
  float* dout = (float*)d_out;

  char* ws = (char*)d_ws;
  size_t off = 0;
  int* flag = (int*)(ws + off); off += 256;
  u16* Wt = (u16*)(ws + off);  off += (size_t)12 * 65536 * 2;
  float* T = (float*)(ws + off); off += (size_t)12 * 65536 * 4;
  float* beff = (float*)(ws + off); off += (size_t)12 * 256 * 4;
  u16* xb = (u16*)(ws + off);  off += (size_t)16384 * 256 * 2;
  float* x = (float*)(ws + off); off += (size_t)16384 * 256 * 4;
  u16* hb = (u16*)(ws + off);  off += (size_t)16384 * 256 * 2;
  u16* gb = (u16*)(ws + off);  off += (size_t)32768 * 256 * 2;
  u16* Qb = (u16*)(ws + off);  off += (size_t)16384 * 256 * 2;
  u16* Kb = (u16*)(ws + off);  off += (size_t)32768 * 256 * 2;
  u16* Vtb = (u16*)(ws + off); off += (size_t)32768 * 256 * 2;
  unsigned* Mbhf = (unsigned*)(ws + off); off += (size_t)16 * 1024 * 1024 / 8;
  unsigned* Mbfg = (unsigned*)(ws + off); off += (size_t)16 * 1024 * 2048 / 8;
  if (ws_size < off) return;

  k_flag<<<1, 64, 0, stream>>>((const unsigned char*)mask_hf, flag);
  k_pack<<<8192, 256, 0, stream>>>(mask_hf, flag, Mbhf);
  k_pack<<<16384, 256, 0, stream>>>(mask_fg, flag, Mbfg);
  k_wc1<<<dim3(256, 12), 256, 0, stream>>>(Wq, Wk, Wv, T);
  k_wc2<<<dim3(16, 12), 256, 0, stream>>>(Wq, Wk, Wv, T, Wt);
  k_bc<<<12, 256, 0, stream>>>(Wq, Wk, Wv, bq, bk, bv, beff);
  k_cvt<<<4096, 256, 0, stream>>>(future, xb, 4194304L);
  k_cvt<<<4096, 256, 0, stream>>>(history, hb, 4194304L);
  k_cvt<<<8192, 256, 0, stream>>>(graph, gb, 8388608L);

  for (int i = 0; i < 4; ++i) {
    const u16* src = (i < 2) ? hb : gb;
    int Mkv = (i < 2) ? 256 : 512;
    int Nk = (i < 2) ? 1024 : 2048;
    const unsigned* mb = (i < 2) ? Mbhf : Mbfg;
    k_proj<<<128 + Mkv, 256, 0, stream>>>(xb, src, Wt, beff, Qb, Kb, Vtb, i, Mkv, Nk);
    k_attn<<<256, 512, 0, stream>>>(Qb, Kb, Vtb, mb, gamma + i * 256, beta + i * 256,
                                    (i == 0) ? future : x, x, xb,
                                    future, dout, (i == 3) ? 1 : 0, Nk);
  }
}

// Round 7
// 837.411 us; speedup vs baseline: 1.0306x; 1.0306x over previous
//
#include <hip/hip_runtime.h>

typedef unsigned short u16;
typedef __bf16 bf16x8 __attribute__((ext_vector_type(8)));
typedef float f32x4 __attribute__((ext_vector_type(4)));

static __device__ __forceinline__ f32x4 mfma16(bf16x8 a, bf16x8 b, f32x4 c) {
  return __builtin_amdgcn_mfma_f32_16x16x32_bf16(a, b, c, 0, 0, 0);
}

static __device__ __forceinline__ u16 f2bf(float f) {
  union { float f; unsigned u; } v; v.f = f;
  unsigned r = v.u + 0x7fffu + ((v.u >> 16) & 1u);
  return (u16)(r >> 16);
}

// async global->LDS DMA, 16B per lane; dest = wave-uniform base + lane*16
static __device__ __forceinline__ void gl2lds16(const u16* g, u16* l) {
  __builtin_amdgcn_global_load_lds(
      (const __attribute__((address_space(1))) unsigned int*)g,
      (__attribute__((address_space(3))) unsigned int*)l, 16, 0, 0);
}

// ---------------- mask element-size probe ----------------
__global__ void k_flag(const unsigned char* __restrict__ m, int* flag) {
  int t = threadIdx.x;  // 64 threads
  unsigned v = (unsigned)m[4*t+1] | (unsigned)m[4*t+2] | (unsigned)m[4*t+3];
  unsigned long long any = __ballot(v != 0);
  if (t == 0) *flag = (any == 0ull) ? 1 : 0;
}

// ---------------- mask bit-pack: elem -> 1 bit ----------------
__global__ __launch_bounds__(256) void k_pack(const void* __restrict__ m,
                                              const int* __restrict__ flagp,
                                              unsigned* __restrict__ out) {
  int flag = *flagp;
  int lane = threadIdx.x & 63, wv = threadIdx.x >> 6;
  long base = (long)blockIdx.x * 2048 + wv * 64 + lane;
#pragma unroll
  for (int it = 0; it < 8; ++it) {
    long elem = base + it * 256;
    bool pred = flag ? (((const int*)m)[elem] != 0)
                     : (((const unsigned char*)m)[elem] != 0);
    unsigned long long bal = __ballot(pred);
    if (lane == 0)  out[elem >> 5] = (unsigned)bal;
    if (lane == 32) out[elem >> 5] = (unsigned)(bal >> 32);
  }
}

// ---------------- weight composition: Weff = W0*W1*W2 (fp32), beff likewise ----------
static __device__ __forceinline__ const float* wbase(int p, const float* Wq,
                                                     const float* Wk, const float* Wv) {
  return (p < 4) ? (Wq + (size_t)p * 196608)
       : (p < 8) ? (Wk + (size_t)(p - 4) * 196608)
                 : (Wv + (size_t)(p - 8) * 196608);
}

// T[p][r][c] = sum_d W0[r][d] * W1[d][c]   (fp32)
__global__ __launch_bounds__(256) void k_wc1(const float* __restrict__ Wq,
                                             const float* __restrict__ Wk,
                                             const float* __restrict__ Wv,
                                             float* __restrict__ T) {
  int p = blockIdx.y, r = blockIdx.x, c = threadIdx.x;
  const float* W0 = wbase(p, Wq, Wk, Wv);
  const float* W1 = W0 + 65536;
  const float* w0r = W0 + (size_t)r * 256;
  float a0 = 0.f, a1 = 0.f, a2 = 0.f, a3 = 0.f;
  for (int d = 0; d < 256; d += 4) {
    a0 += w0r[d]     * W1[(size_t)d * 256 + c];
    a1 += w0r[d + 1] * W1[(size_t)(d + 1) * 256 + c];
    a2 += w0r[d + 2] * W1[(size_t)(d + 2) * 256 + c];
    a3 += w0r[d + 3] * W1[(size_t)(d + 3) * 256 + c];
  }
  T[((size_t)p * 256 + r) * 256 + c] = (a0 + a1) + (a2 + a3);
}

// Wt[p][e][d] = bf16( sum_c T[p][d][c] * W2[c][e] )   (transposed-out for the GEMM)
__global__ __launch_bounds__(256) void k_wc2(const float* __restrict__ Wq,
                                             const float* __restrict__ Wk,
                                             const float* __restrict__ Wv,
                                             const float* __restrict__ T,
                                             u16* __restrict__ Wt) {
  int p = blockIdx.y, e0 = blockIdx.x << 4, d = threadIdx.x;
  const float* W2 = wbase(p, Wq, Wk, Wv) + 131072;
  __shared__ __align__(16) float sw[256][16];
#pragma unroll
  for (int j = 0; j < 4; ++j)
    *(float4*)&sw[d][j * 4] = *(const float4*)&W2[(size_t)d * 256 + e0 + j * 4];
  __syncthreads();
  const float* Tr = T + ((size_t)p * 256 + d) * 256;
  float acc[16];
#pragma unroll
  for (int j = 0; j < 16; ++j) acc[j] = 0.f;
  for (int c = 0; c < 256; c += 4) {
    float4 tv = *(const float4*)&Tr[c];
#pragma unroll
    for (int j = 0; j < 16; ++j) {
      acc[j] += tv.x * sw[c][j];
      acc[j] += tv.y * sw[c + 1][j];
      acc[j] += tv.z * sw[c + 2][j];
      acc[j] += tv.w * sw[c + 3][j];
    }
  }
#pragma unroll
  for (int j = 0; j < 16; ++j)
    Wt[((size_t)p * 256 + e0 + j) * 256 + d] = f2bf(acc[j]);
}

// beff[p][e] = ((b0*W1 + b1)*W2 + b2)[e]
__global__ __launch_bounds__(256) void k_bc(const float* __restrict__ Wq,
                                            const float* __restrict__ Wk,
                                            const float* __restrict__ Wv,
                                            const float* __restrict__ bq,
                                            const float* __restrict__ bk,
                                            const float* __restrict__ bv,
                                            float* __restrict__ beff) {
  int p = blockIdx.x, t = threadIdx.x;
  const float* W0 = wbase(p, Wq, Wk, Wv);
  const float* W1 = W0 + 65536;
  const float* W2 = W0 + 131072;
  const float* b = (p < 4) ? (bq + p * 768)
                 : (p < 8) ? (bk + (p - 4) * 768)
                           : (bv + (p - 8) * 768);
  __shared__ float s1[256];
  float a = 0.f;
  for (int d = 0; d < 256; ++d) a += b[d] * W1[(size_t)d * 256 + t];
  s1[t] = a + b[256 + t];
  __syncthreads();
  float a2 = 0.f;
  for (int c = 0; c < 256; ++c) a2 += s1[c] * W2[(size_t)c * 256 + t];
  beff[p * 256 + t] = a2 + b[512 + t];
}

// ---------------- fused fp32 -> bf16 convert for future/history/graph ----------------
__global__ __launch_bounds__(256) void k_cvt3(const float* __restrict__ future,
                                              const float* __restrict__ history,
                                              const float* __restrict__ graph,
                                              u16* __restrict__ xb,
                                              u16* __restrict__ hb,
                                              u16* __restrict__ gb) {
  int bid = blockIdx.x;
  const float* src; u16* dst; long base;
  if (bid < 4096)      { src = future;  dst = xb; base = (long)bid * 1024; }
  else if (bid < 8192) { src = history; dst = hb; base = (long)(bid - 4096) * 1024; }
  else                 { src = graph;   dst = gb; base = (long)(bid - 8192) * 1024; }
  long i = base + threadIdx.x * 4;
  float4 v = *(const float4*)(src + i);
  union { u16 u[4]; uint2 q; } o;
  o.u[0] = f2bf(v.x); o.u[1] = f2bf(v.y); o.u[2] = f2bf(v.z); o.u[3] = f2bf(v.w);
  *(uint2*)(dst + i) = o.q;
}

// ---------------- projection: W-in-registers, X DMA dbuf, 1 barrier/tile ----------------
template<int MODE>
static __device__ __forceinline__ void proj_body(
    const u16* __restrict__ X, const u16* __restrict__ Wg,
    const float* __restrict__ bias, u16* __restrict__ out, int Nk,
    int t0, int nt, u16 (*Xs)[64][256]) {
  int t = threadIdx.x, lane = t & 63, w = t >> 6, g = lane >> 4, li = lane & 15;
  int rbase = (w << 1) | (lane >> 5);            // 0..7
  int scg = (lane & 31) ^ rbase;                 // pre-swizzled source col-group

  // preload full W into registers
  bf16x8 wf[8][4];
#pragma unroll
  for (int kk = 0; kk < 8; ++kk)
#pragma unroll
    for (int f = 0; f < 4; ++f)
      wf[kk][f] = *(const bf16x8*)&Wg[(size_t)(w * 64 + f * 16 + li) * 256 + kk * 32 + g * 8];

  // stage tile t0 -> buf0
  {
    const u16* sb = X + ((long)t0 * 64 + rbase) * 256 + (scg << 3);
    u16* db = &Xs[0][0][0] + (w << 9);
#pragma unroll
    for (int r8 = 0; r8 < 8; ++r8) gl2lds16(sb + r8 * 2048, db + r8 * 2048);
  }
  asm volatile("s_waitcnt vmcnt(0)" ::: "memory");
  __syncthreads();

  for (int ti = 0; ti < nt; ++ti) {
    int p = ti & 1;
    if (ti + 1 < nt) {   // DMA next tile into the other buffer
      const u16* sb = X + ((long)(t0 + ti + 1) * 64 + rbase) * 256 + (scg << 3);
      u16* db = &Xs[p ^ 1][0][0] + (w << 9);
#pragma unroll
      for (int r8 = 0; r8 < 8; ++r8) gl2lds16(sb + r8 * 2048, db + r8 * 2048);
    }
    f32x4 acc[4][4];
#pragma unroll
    for (int i = 0; i < 4; ++i)
#pragma unroll
      for (int jj = 0; jj < 4; ++jj) acc[i][jj] = (f32x4){0.f, 0.f, 0.f, 0.f};
#pragma unroll
    for (int kk = 0; kk < 8; ++kk) {
      bf16x8 xf[4];
#pragma unroll
      for (int f = 0; f < 4; ++f)
        xf[f] = *(const bf16x8*)&Xs[p][f * 16 + li][((kk * 4 + g) ^ (li & 7)) << 3];
#pragma unroll
      for (int i = 0; i < 4; ++i)
#pragma unroll
        for (int jj = 0; jj < 4; ++jj)
          acc[i][jj] = (MODE == 0) ? mfma16(xf[i], wf[kk][jj], acc[i][jj])
                                   : mfma16(wf[kk][i], xf[jj], acc[i][jj]);
    }
    asm volatile("s_waitcnt vmcnt(0)" ::: "memory");
    __syncthreads();
    long row0 = (long)(t0 + ti) * 64;
    if (MODE == 0) {
#pragma unroll
      for (int i = 0; i < 4; ++i)
#pragma unroll
        for (int jj = 0; jj < 4; ++jj)
#pragma unroll
          for (int r = 0; r < 4; ++r) {
            int R = i * 16 + g * 4 + r, C = w * 64 + jj * 16 + li;
            out[(row0 + R) * 256 + C] = f2bf(acc[i][jj][r] + bias[C]);
          }
    } else {
      long b = row0 / Nk, rb = row0 - b * Nk;
#pragma unroll
      for (int i = 0; i < 4; ++i)
#pragma unroll
        for (int jj = 0; jj < 4; ++jj)
#pragma unroll
          for (int r = 0; r < 4; ++r) {
            int e = w * 64 + i * 16 + g * 4 + r, xr = jj * 16 + li;
            out[(b * 256 + e) * (long)Nk + rb + xr] = f2bf(acc[i][jj][r] + bias[e]);
          }
    }
  }
}

// One dispatch per layer: Q blocks [0,128), K blocks [128,128+Mkv/2), V rest. 2 tiles/block.
__global__ __launch_bounds__(256, 2) void k_proj(
    const u16* __restrict__ Xq, const u16* __restrict__ Xkv,
    const u16* __restrict__ Wt, const float* __restrict__ beff,
    u16* __restrict__ Qb, u16* __restrict__ Kb, u16* __restrict__ Vt,
    int layer, int Mkv, int Nk) {
  __shared__ __align__(16) u16 Xs[2][64][256];
  int u = blockIdx.x, h = Mkv >> 1;
  if (u < 128)
    proj_body<0>(Xq, Wt + (size_t)layer * 65536, beff + layer * 256, Qb, 0,
                 u * 2, 2, Xs);
  else if (u < 128 + h)
    proj_body<0>(Xkv, Wt + (size_t)(4 + layer) * 65536, beff + (4 + layer) * 256, Kb, 0,
                 (u - 128) * 2, 2, Xs);
  else
    proj_body<1>(Xkv, Wt + (size_t)(8 + layer) * 65536, beff + (8 + layer) * 256, Vt, Nk,
                 (u - 128 - h) * 2, 2, Xs);
}

// ---------------- flash attention v7: optional k-split for 2 blocks/CU ----------------
// SPLIT=1: grid 512, block (b, qtile, ks) covers k-half ks; writes UNNORMALIZED O
// partial (fp32) + row-sum l to workspace; k_amrg merges + LN + residual.
// SPLIT=0: grid 256, full epilogue in-kernel (R6 path).
// Inner loop identical to R6 (verified): single 64KB K/V buffer, 2 barriers/iter,
// issue-early reg staging, swapped QK, in-register P redistribution, swizzled LDS.
template<int SPLIT>
__global__ __launch_bounds__(512, 2) void k_attn(
    const u16* __restrict__ Qb, const u16* __restrict__ Kb, const u16* __restrict__ Vt,
    const unsigned* __restrict__ Mb,
    const float* __restrict__ gamma, const float* __restrict__ beta,
    const float* __restrict__ rin, float* xres, u16* xbout,
    const float* __restrict__ future, float* __restrict__ dout, int last, int Nk,
    float* __restrict__ Op, float* __restrict__ Lg) {
  __shared__ __align__(16) char RAW[66816];  // K 32KB | V 32KB; epilogue aliases all

  int t = threadIdx.x, lane = t & 63, w = t >> 6;
  int qt = w >> 1, s = w & 1;
  int g = lane >> 4, li = lane & 15;
  int sw = li & 7;

  // XCD-bijective swizzle: XCD x owns batches {2x, 2x+1} -> K/V stays in its L2.
  int n = blockIdx.x;
  int b = ((n & 7) << 1) | ((n >> 3) & 1);
  int q0 = ((n >> 4) & 15) << 6;
  int ks = SPLIT ? (n >> 8) : 0;
  int half = SPLIT ? (Nk >> 1) : Nk;

  int W = Nk >> 5, nc = half >> 6;

  const u16* Kg = Kb + (long)b * Nk * 256 + (long)ks * half * 256;
  const u16* Vg = Vt + (long)b * 256 * (long)Nk + ks * half;
  const unsigned* Mg = Mb + ((long)b * 1024 + q0 + qt * 16 + li) * W + ks * (half >> 5);
  const u16* Qg = Qb + ((long)b * 1024 + q0 + qt * 16 + li) * 256 + g * 8;

  // Per-thread staging slots (4 K + 4 V), swizzle on the GLOBAL source address.
  int sA = t, sB = 512 + t, sC = 1024 + t, sD = 1536 + t;
  const u16* KgA = Kg + (long)(sA >> 5) * 256 + (((sA & 31) ^ ((sA >> 5) & 7)) << 3);
  const u16* KgB = Kg + (long)(sB >> 5) * 256 + (((sB & 31) ^ ((sB >> 5) & 7)) << 3);
  const u16* KgC = Kg + (long)(sC >> 5) * 256 + (((sC & 31) ^ ((sC >> 5) & 7)) << 3);
  const u16* KgD = Kg + (long)(sD >> 5) * 256 + (((sD & 31) ^ ((sD >> 5) & 7)) << 3);
  const u16* VgA = Vg + (long)(sA >> 3) * Nk + (((sA & 7) ^ ((sA >> 3) & 7)) << 3);
  const u16* VgB = Vg + (long)(sB >> 3) * Nk + (((sB & 7) ^ ((sB >> 3) & 7)) << 3);
  const u16* VgC = Vg + (long)(sC >> 3) * Nk + (((sC & 7) ^ ((sC >> 3) & 7)) << 3);
  const u16* VgD = Vg + (long)(sD >> 3) * Nk + (((sD & 7) ^ ((sD >> 3) & 7)) << 3);

  u16* Kw = (u16*)RAW;
  u16* Vw = Kw + 16384;

  // ---- prologue: chunk 0 -> regs, Q frags, chunk 0 -> buf, barrier ----
  uint4 k0 = *(const uint4*)KgA, k1 = *(const uint4*)KgB;
  uint4 k2 = *(const uint4*)KgC, k3 = *(const uint4*)KgD;
  uint4 v0 = *(const uint4*)VgA, v1 = *(const uint4*)VgB;
  uint4 v2 = *(const uint4*)VgC, v3 = *(const uint4*)VgD;
  bf16x8 qf[8];
#pragma unroll
  for (int kc = 0; kc < 8; ++kc) qf[kc] = *(const bf16x8*)(Qg + kc * 32);
  *(uint4*)&Kw[sA * 8] = k0; *(uint4*)&Kw[sB * 8] = k1;
  *(uint4*)&Kw[sC * 8] = k2; *(uint4*)&Kw[sD * 8] = k3;
  *(uint4*)&Vw[sA * 8] = v0; *(uint4*)&Vw[sB * 8] = v1;
  *(uint4*)&Vw[sC * 8] = v2; *(uint4*)&Vw[sD * 8] = v3;
  __syncthreads();

  f32x4 O[16];
#pragma unroll
  for (int dt = 0; dt < 16; ++dt) O[dt] = (f32x4){0.f, 0.f, 0.f, 0.f};
  float lsum = 0.f;

  for (int ci = 0; ci < nc; ++ci) {
    long cb2 = (long)((ci + 1 < nc) ? ci + 1 : nc - 1) << 6;
    k0 = *(const uint4*)(KgA + cb2 * 256); k1 = *(const uint4*)(KgB + cb2 * 256);
    k2 = *(const uint4*)(KgC + cb2 * 256); k3 = *(const uint4*)(KgD + cb2 * 256);
    v0 = *(const uint4*)(VgA + cb2);       v1 = *(const uint4*)(VgB + cb2);
    v2 = *(const uint4*)(VgC + cb2);       v3 = *(const uint4*)(VgD + cb2);
    unsigned mw = Mg[(ci << 1) + s];

    const u16* Kr0 = Kw + (s * 32 + li) * 256;
    const u16* Kr1 = Kr0 + 4096;
    f32x4 st0 = (f32x4){0.f, 0.f, 0.f, 0.f}, st1 = (f32x4){0.f, 0.f, 0.f, 0.f};
#pragma unroll
    for (int kc = 0; kc < 8; ++kc) {
      int co = ((kc * 4 + g) ^ sw) << 3;
      st0 = mfma16(*(const bf16x8*)&Kr0[co], qf[kc], st0);
      st1 = mfma16(*(const bf16x8*)&Kr1[co], qf[kc], st1);
    }
    float e0[4], e1[4];
#pragma unroll
    for (int r = 0; r < 4; ++r) {
      bool m0 = (mw >> (g * 4 + r)) & 1u;
      bool m1 = (mw >> (16 + g * 4 + r)) & 1u;
      e0[r] = m0 ? 0.f : __expf(st0[r] * 0.0625f);
      e1[r] = m1 ? 0.f : __expf(st1[r] * 0.0625f);
      lsum += e0[r] + e1[r];
    }
    unsigned u00 = (unsigned)f2bf(e0[0]) | ((unsigned)f2bf(e0[1]) << 16);
    unsigned u01 = (unsigned)f2bf(e0[2]) | ((unsigned)f2bf(e0[3]) << 16);
    unsigned u10 = (unsigned)f2bf(e1[0]) | ((unsigned)f2bf(e1[1]) << 16);
    unsigned u11 = (unsigned)f2bf(e1[2]) | ((unsigned)f2bf(e1[3]) << 16);
    int s0l = ((g & 1) << 5) + li;
    unsigned a0 = __shfl(u00, s0l),      a1 = __shfl(u01, s0l);
    unsigned a2 = __shfl(u00, s0l + 16), a3 = __shfl(u01, s0l + 16);
    unsigned c0 = __shfl(u10, s0l),      c1 = __shfl(u11, s0l);
    unsigned c2 = __shfl(u10, s0l + 16), c3 = __shfl(u11, s0l + 16);
    union { unsigned u[4]; bf16x8 v; } pa;
    bool hi = (g >= 2);
    pa.u[0] = hi ? c0 : a0; pa.u[1] = hi ? c1 : a1;
    pa.u[2] = hi ? c2 : a2; pa.u[3] = hi ? c3 : a3;
    const u16* Vr = Vw + li * 64 + (((s * 4 + g) ^ sw) << 3);
#pragma unroll
    for (int dt = 0; dt < 16; ++dt) {
      bf16x8 bv = *(const bf16x8*)&Vr[dt * 1024];
      O[dt] = mfma16(pa.v, bv, O[dt]);
    }
    __syncthreads();   // all reads of this chunk done
    if (ci + 1 < nc) { // write next chunk into the (single) buffer
      *(uint4*)&Kw[sA * 8] = k0; *(uint4*)&Kw[sB * 8] = k1;
      *(uint4*)&Kw[sC * 8] = k2; *(uint4*)&Kw[sD * 8] = k3;
      *(uint4*)&Vw[sA * 8] = v0; *(uint4*)&Vw[sB * 8] = v1;
      *(uint4*)&Vw[sC * 8] = v2; *(uint4*)&Vw[sD * 8] = v3;
      __syncthreads();
    }
  }

  // ---- merge the two in-block s-halves in LDS ----
  float* Om = (float*)RAW;             // [4][16][260]
  float* Lm = (float*)(RAW + 66560);   // [4][16]
  lsum += __shfl_xor(lsum, 16);
  lsum += __shfl_xor(lsum, 32);        // all lanes: l[q=li] for this s-half
  if (s == 1) {
#pragma unroll
    for (int dt = 0; dt < 16; ++dt)
#pragma unroll
      for (int r = 0; r < 4; ++r)
        Om[(qt * 16 + g * 4 + r) * 260 + dt * 16 + li] = O[dt][r];
    if (g == 0) Lm[qt * 16 + li] = lsum;
  }
  __syncthreads();
  if (s == 0) {
    float ltot = lsum + Lm[qt * 16 + li];
#pragma unroll
    for (int dt = 0; dt < 16; ++dt)
#pragma unroll
      for (int r = 0; r < 4; ++r)
        O[dt][r] += Om[(qt * 16 + g * 4 + r) * 260 + dt * 16 + li];

    if (SPLIT) {
      // write UNNORMALIZED partial + row-sum; k_amrg finishes
      if (g == 0) Lg[(long)ks * 16384 + b * 1024 + q0 + qt * 16 + li] = ltot;
      float* Od = Op + ((long)ks * 16384 + (long)b * 1024 + q0) * 256;
#pragma unroll
      for (int dt = 0; dt < 16; ++dt) {
        int d = dt * 16 + li;
#pragma unroll
        for (int r = 0; r < 4; ++r)
          Od[(qt * 16 + g * 4 + r) * 256 + d] = O[dt][r];
      }
    } else {
      float rl = 1.f / fmaxf(ltot, 1e-30f);
      float rq[4];
#pragma unroll
      for (int r = 0; r < 4; ++r) rq[r] = __shfl(rl, g * 4 + r);
      float sm[4] = {0.f, 0.f, 0.f, 0.f}, s2[4] = {0.f, 0.f, 0.f, 0.f};
#pragma unroll
      for (int dt = 0; dt < 16; ++dt)
#pragma unroll
        for (int r = 0; r < 4; ++r) {
          float y = O[dt][r] * rq[r];
          O[dt][r] = y;
          sm[r] += y; s2[r] += y * y;
        }
#pragma unroll
      for (int r = 0; r < 4; ++r) {
        float a = sm[r], c = s2[r];
        a += __shfl_xor(a, 1); a += __shfl_xor(a, 2);
        a += __shfl_xor(a, 4); a += __shfl_xor(a, 8);
        c += __shfl_xor(c, 1); c += __shfl_xor(c, 2);
        c += __shfl_xor(c, 4); c += __shfl_xor(c, 8);
        float m = a * (1.f / 256.f);
        sm[r] = m;
        s2[r] = rsqrtf(c * (1.f / 256.f) - m * m + 1e-5f);
      }
#pragma unroll
      for (int dt = 0; dt < 16; ++dt) {
        int d = dt * 16 + li;
        float gm = gamma[d], bt = beta[d];
#pragma unroll
        for (int r = 0; r < 4; ++r) {
          int q = q0 + qt * 16 + g * 4 + r;
          long idx = ((long)b * 1024 + q) * 256 + d;
          float o = (O[dt][r] - sm[r]) * s2[r] * gm + bt + rin[idx];
          if (last) dout[idx] = o + future[idx];
          else { xres[idx] = o; xbout[idx] = f2bf(o); }
        }
      }
    }
  }
}

// ---------------- k-split merge: normalize + LayerNorm + residual ----------------
// Grid 1024 x 256thr. Wave: 4 rows (sub = lane>>4), lane li covers d = j*64+li*4.
__global__ __launch_bounds__(256) void k_amrg(
    const float* __restrict__ Op, const float* __restrict__ Lg,
    const float* __restrict__ gamma, const float* __restrict__ beta,
    const float* __restrict__ rin, float* xres, u16* xbout,
    const float* __restrict__ future, float* __restrict__ dout, int last) {
  int t = threadIdx.x, lane = t & 63, w = t >> 6;
  int sub = lane >> 4, li = lane & 15;
  long row = (long)blockIdx.x * 16 + w * 4 + sub;
  const float* o0 = Op + row * 256;
  const float* o1 = Op + 16384L * 256 + row * 256;
  float rl = 1.f / fmaxf(Lg[row] + Lg[16384 + row], 1e-30f);
  float4 y[4];
  float sm = 0.f, s2 = 0.f;
#pragma unroll
  for (int j = 0; j < 4; ++j) {
    int d0 = j * 64 + li * 4;
    float4 a = *(const float4*)(o0 + d0);
    float4 c = *(const float4*)(o1 + d0);
    float4 yv;
    yv.x = (a.x + c.x) * rl; yv.y = (a.y + c.y) * rl;
    yv.z = (a.z + c.z) * rl; yv.w = (a.w + c.w) * rl;
    y[j] = yv;
    sm += yv.x + yv.y + yv.z + yv.w;
    s2 += yv.x * yv.x + yv.y * yv.y + yv.z * yv.z + yv.w * yv.w;
  }
  sm += __shfl_xor(sm, 1); sm += __shfl_xor(sm, 2);
  sm += __shfl_xor(sm, 4); sm += __shfl_xor(sm, 8);
  s2 += __shfl_xor(s2, 1); s2 += __shfl_xor(s2, 2);
  s2 += __shfl_xor(s2, 4); s2 += __shfl_xor(s2, 8);
  float mu = sm * (1.f / 256.f);
  float rstd = rsqrtf(s2 * (1.f / 256.f) - mu * mu + 1e-5f);
#pragma unroll
  for (int j = 0; j < 4; ++j) {
    int d0 = j * 64 + li * 4;
    float4 g4 = *(const float4*)(gamma + d0);
    float4 b4 = *(const float4*)(beta + d0);
    float4 r4 = *(const float4*)(rin + row * 256 + d0);
    float4 o;
    o.x = (y[j].x - mu) * rstd * g4.x + b4.x + r4.x;
    o.y = (y[j].y - mu) * rstd * g4.y + b4.y + r4.y;
    o.z = (y[j].z - mu) * rstd * g4.z + b4.z + r4.z;
    o.w = (y[j].w - mu) * rstd * g4.w + b4.w + r4.w;
    if (last) {
      float4 f4 = *(const float4*)(future + row * 256 + d0);
      o.x += f4.x; o.y += f4.y; o.z += f4.z; o.w += f4.w;
      *(float4*)(dout + row * 256 + d0) = o;
    } else {
      *(float4*)(xres + row * 256 + d0) = o;
      union { u16 u[4]; uint2 q; } pk;
      pk.u[0] = f2bf(o.x); pk.u[1] = f2bf(o.y);
      pk.u[2] = f2bf(o.z); pk.u[3] = f2bf(o.w);
      *(uint2*)(xbout + row * 256 + d0) = pk.q;
    }
  }
}

// ---------------- host ----------------
extern "C" void kernel_launch(void* const* d_in, const int* in_sizes, int n_in,
                              void* d_out, int out_size, void* d_ws, size_t ws_size,
                              hipStream_t stream) {
  const float* future  = (const float*)d_in[0];
  const float* history = (const float*)d_in[1];
  const float* graph   = (const float*)d_in[2];
  const void*  mask_hf = d_in[3];
  const void*  mask_fg = d_in[4];
  const float* Wq = (const float*)d_in[5];
  const float* bq = (const float*)d_in[6];
  const float* Wk = (const float*)d_in[7];
  const float* bk = (const float*)d_in[8];
  const float* Wv = (const float*)d_in[9];
  const float* bv = (const float*)d_in[10];
  const float* gamma = (const float*)d_in[11];
  const float* beta  = (const float*)d_in[12];
  float* dout = (float*)d_out;

  char* ws = (char*)d_ws;
  size_t off = 0;
  int* flag = (int*)(ws + off); off += 256;
  u16* Wt = (u16*)(ws + off);  off += (size_t)12 * 65536 * 2;
  float* T = (float*)(ws + off); off += (size_t)12 * 65536 * 4;
  float* beff = (float*)(ws + off); off += (size_t)12 * 256 * 4;
  u16* xb = (u16*)(ws + off);  off += (size_t)16384 * 256 * 2;
  float* x = (float*)(ws + off); off += (size_t)16384 * 256 * 4;
  u16* hb = (u16*)(ws + off);  off += (size_t)16384 * 256 * 2;
  u16* gb = (u16*)(ws + off);  off += (size_t)32768 * 256 * 2;
  u16* Qb = (u16*)(ws + off);  off += (size_t)16384 * 256 * 2;
  u16* Kb = (u16*)(ws + off);  off += (size_t)32768 * 256 * 2;
  u16* Vtb = (u16*)(ws + off); off += (size_t)32768 * 256 * 2;
  unsigned* Mbhf = (unsigned*)(ws + off); off += (size_t)16 * 1024 * 1024 / 8;
  unsigned* Mbfg = (unsigned*)(ws + off); off += (size_t)16 * 1024 * 2048 / 8;
  if (ws_size < off) return;
  // k-split partials (optional; fall back to in-kernel epilogue if ws too small)
  float* Op = (float*)(ws + off); off += (size_t)2 * 16384 * 256 * 4;
  float* Lg = (float*)(ws + off); off += (size_t)2 * 16384 * 4;
  int split = (ws_size >= off) ? 1 : 0;

  k_flag<<<1, 64, 0, stream>>>((const unsigned char*)mask_hf, flag);
  k_pack<<<8192, 256, 0, stream>>>(mask_hf, flag, Mbhf);
  k_pack<<<16384, 256, 0, stream>>>(mask_fg, flag, Mbfg);
  k_wc1<<<dim3(256, 12), 256, 0, stream>>>(Wq, Wk, Wv, T);
  k_wc2<<<dim3(16, 12), 256, 0, stream>>>(Wq, Wk, Wv, T, Wt);
  k_bc<<<12, 256, 0, stream>>>(Wq, Wk, Wv, bq, bk, bv, beff);
  k_cvt3<<<16384, 256, 0, stream>>>(future, history, graph, xb, hb, gb);

  for (int i = 0; i < 4; ++i) {
    const u16* src = (i < 2) ? hb : gb;
    int Mkv = (i < 2) ? 256 : 512;
    int Nk = (i < 2) ? 1024 : 2048;
    const unsigned* mb = (i < 2) ? Mbhf : Mbfg;
    const float* rin = (i == 0) ? future : x;
    int last = (i == 3) ? 1 : 0;
    k_proj<<<128 + Mkv, 256, 0, stream>>>(xb, src, Wt, beff, Qb, Kb, Vtb, i, Mkv, Nk);
    if (split) {
      k_attn<1><<<512, 512, 0, stream>>>(Qb, Kb, Vtb, mb, gamma + i * 256, beta + i * 256,
                                         rin, x, xb, future, dout, last, Nk, Op, Lg);
      k_amrg<<<1024, 256, 0, stream>>>(Op, Lg, gamma + i * 256, beta + i * 256,
                                       rin, x, xb, future, dout, last);
    } else {
      k_attn<0><<<256, 512, 0, stream>>>(Qb, Kb, Vtb, mb, gamma + i * 256, beta + i * 256,
                                         rin, x, xb, future, dout, last, Nk, Op, Lg);
    }
  }
}

// Round 8
// 812.083 us; speedup vs baseline: 1.0628x; 1.0312x over previous
//
#include <hip/hip_runtime.h>

typedef unsigned short u16;
typedef __bf16 bf16x8 __attribute__((ext_vector_type(8)));
typedef float f32x4 __attribute__((ext_vector_type(4)));

static __device__ __forceinline__ f32x4 mfma16(bf16x8 a, bf16x8 b, f32x4 c) {
  return __builtin_amdgcn_mfma_f32_16x16x32_bf16(a, b, c, 0, 0, 0);
}

static __device__ __forceinline__ u16 f2bf(float f) {
  union { float f; unsigned u; } v; v.f = f;
  unsigned r = v.u + 0x7fffu + ((v.u >> 16) & 1u);
  return (u16)(r >> 16);
}

// async global->LDS DMA, 16B per lane; dest = wave-uniform base + lane*16
static __device__ __forceinline__ void gl2lds16(const u16* g, u16* l) {
  __builtin_amdgcn_global_load_lds(
      (const __attribute__((address_space(1))) unsigned int*)g,
      (__attribute__((address_space(3))) unsigned int*)l, 16, 0, 0);
}

// ---------------- mask element-size probe ----------------
__global__ void k_flag(const unsigned char* __restrict__ m, int* flag) {
  int t = threadIdx.x;  // 64 threads
  unsigned v = (unsigned)m[4*t+1] | (unsigned)m[4*t+2] | (unsigned)m[4*t+3];
  unsigned long long any = __ballot(v != 0);
  if (t == 0) *flag = (any == 0ull) ? 1 : 0;
}

// ---------------- mask bit-pack: elem -> 1 bit ----------------
__global__ __launch_bounds__(256) void k_pack(const void* __restrict__ m,
                                              const int* __restrict__ flagp,
                                              unsigned* __restrict__ out) {
  int flag = *flagp;
  int lane = threadIdx.x & 63, wv = threadIdx.x >> 6;
  long base = (long)blockIdx.x * 2048 + wv * 64 + lane;
#pragma unroll
  for (int it = 0; it < 8; ++it) {
    long elem = base + it * 256;
    bool pred = flag ? (((const int*)m)[elem] != 0)
                     : (((const unsigned char*)m)[elem] != 0);
    unsigned long long bal = __ballot(pred);
    if (lane == 0)  out[elem >> 5] = (unsigned)bal;
    if (lane == 32) out[elem >> 5] = (unsigned)(bal >> 32);
  }
}

// ---------------- weight composition: Weff = W0*W1*W2 (fp32), beff likewise ----------
static __device__ __forceinline__ const float* wbase(int p, const float* Wq,
                                                     const float* Wk, const float* Wv) {
  return (p < 4) ? (Wq + (size_t)p * 196608)
       : (p < 8) ? (Wk + (size_t)(p - 4) * 196608)
                 : (Wv + (size_t)(p - 8) * 196608);
}

// T[p][r][c] = sum_d W0[r][d] * W1[d][c]   (fp32)
__global__ __launch_bounds__(256) void k_wc1(const float* __restrict__ Wq,
                                             const float* __restrict__ Wk,
                                             const float* __restrict__ Wv,
                                             float* __restrict__ T) {
  int p = blockIdx.y, r = blockIdx.x, c = threadIdx.x;
  const float* W0 = wbase(p, Wq, Wk, Wv);
  const float* W1 = W0 + 65536;
  const float* w0r = W0 + (size_t)r * 256;
  float a0 = 0.f, a1 = 0.f, a2 = 0.f, a3 = 0.f;
  for (int d = 0; d < 256; d += 4) {
    a0 += w0r[d]     * W1[(size_t)d * 256 + c];
    a1 += w0r[d + 1] * W1[(size_t)(d + 1) * 256 + c];
    a2 += w0r[d + 2] * W1[(size_t)(d + 2) * 256 + c];
    a3 += w0r[d + 3] * W1[(size_t)(d + 3) * 256 + c];
  }
  T[((size_t)p * 256 + r) * 256 + c] = (a0 + a1) + (a2 + a3);
}

// Wt[p][e][d] = bf16( sum_c T[p][d][c] * W2[c][e] )   (transposed-out for the GEMM)
__global__ __launch_bounds__(256) void k_wc2(const float* __restrict__ Wq,
                                             const float* __restrict__ Wk,
                                             const float* __restrict__ Wv,
                                             const float* __restrict__ T,
                                             u16* __restrict__ Wt) {
  int p = blockIdx.y, e0 = blockIdx.x << 4, d = threadIdx.x;
  const float* W2 = wbase(p, Wq, Wk, Wv) + 131072;
  __shared__ __align__(16) float sw[256][16];
#pragma unroll
  for (int j = 0; j < 4; ++j)
    *(float4*)&sw[d][j * 4] = *(const float4*)&W2[(size_t)d * 256 + e0 + j * 4];
  __syncthreads();
  const float* Tr = T + ((size_t)p * 256 + d) * 256;
  float acc[16];
#pragma unroll
  for (int j = 0; j < 16; ++j) acc[j] = 0.f;
  for (int c = 0; c < 256; c += 4) {
    float4 tv = *(const float4*)&Tr[c];
#pragma unroll
    for (int j = 0; j < 16; ++j) {
      acc[j] += tv.x * sw[c][j];
      acc[j] += tv.y * sw[c + 1][j];
      acc[j] += tv.z * sw[c + 2][j];
      acc[j] += tv.w * sw[c + 3][j];
    }
  }
#pragma unroll
  for (int j = 0; j < 16; ++j)
    Wt[((size_t)p * 256 + e0 + j) * 256 + d] = f2bf(acc[j]);
}

// beff[p][e] = ((b0*W1 + b1)*W2 + b2)[e]
__global__ __launch_bounds__(256) void k_bc(const float* __restrict__ Wq,
                                            const float* __restrict__ Wk,
                                            const float* __restrict__ Wv,
                                            const float* __restrict__ bq,
                                            const float* __restrict__ bk,
                                            const float* __restrict__ bv,
                                            float* __restrict__ beff) {
  int p = blockIdx.x, t = threadIdx.x;
  const float* W0 = wbase(p, Wq, Wk, Wv);
  const float* W1 = W0 + 65536;
  const float* W2 = W0 + 131072;
  const float* b = (p < 4) ? (bq + p * 768)
                 : (p < 8) ? (bk + (p - 4) * 768)
                           : (bv + (p - 8) * 768);
  __shared__ float s1[256];
  float a = 0.f;
  for (int d = 0; d < 256; ++d) a += b[d] * W1[(size_t)d * 256 + t];
  s1[t] = a + b[256 + t];
  __syncthreads();
  float a2 = 0.f;
  for (int c = 0; c < 256; ++c) a2 += s1[c] * W2[(size_t)c * 256 + t];
  beff[p * 256 + t] = a2 + b[512 + t];
}

// ---------------- fused fp32 -> bf16 convert for future/history/graph ----------------
__global__ __launch_bounds__(256) void k_cvt3(const float* __restrict__ future,
                                              const float* __restrict__ history,
                                              const float* __restrict__ graph,
                                              u16* __restrict__ xb,
                                              u16* __restrict__ hb,
                                              u16* __restrict__ gb) {
  int bid = blockIdx.x;
  const float* src; u16* dst; long base;
  if (bid < 4096)      { src = future;  dst = xb; base = (long)bid * 1024; }
  else if (bid < 8192) { src = history; dst = hb; base = (long)(bid - 4096) * 1024; }
  else                 { src = graph;   dst = gb; base = (long)(bid - 8192) * 1024; }
  long i = base + threadIdx.x * 4;
  float4 v = *(const float4*)(src + i);
  union { u16 u[4]; uint2 q; } o;
  o.u[0] = f2bf(v.x); o.u[1] = f2bf(v.y); o.u[2] = f2bf(v.z); o.u[3] = f2bf(v.w);
  *(uint2*)(dst + i) = o.q;
}

// ---------------- projection: W-in-registers, X DMA dbuf, 1 barrier/tile ----------------
template<int MODE>
static __device__ __forceinline__ void proj_body(
    const u16* __restrict__ X, const u16* __restrict__ Wg,
    const float* __restrict__ bias, u16* __restrict__ out, int Nk,
    int t0, int nt, u16 (*Xs)[64][256]) {
  int t = threadIdx.x, lane = t & 63, w = t >> 6, g = lane >> 4, li = lane & 15;
  int rbase = (w << 1) | (lane >> 5);            // 0..7
  int scg = (lane & 31) ^ rbase;                 // pre-swizzled source col-group

  // preload full W into registers
  bf16x8 wf[8][4];
#pragma unroll
  for (int kk = 0; kk < 8; ++kk)
#pragma unroll
    for (int f = 0; f < 4; ++f)
      wf[kk][f] = *(const bf16x8*)&Wg[(size_t)(w * 64 + f * 16 + li) * 256 + kk * 32 + g * 8];

  // stage tile t0 -> buf0
  {
    const u16* sb = X + ((long)t0 * 64 + rbase) * 256 + (scg << 3);
    u16* db = &Xs[0][0][0] + (w << 9);
#pragma unroll
    for (int r8 = 0; r8 < 8; ++r8) gl2lds16(sb + r8 * 2048, db + r8 * 2048);
  }
  asm volatile("s_waitcnt vmcnt(0)" ::: "memory");
  __syncthreads();

  for (int ti = 0; ti < nt; ++ti) {
    int p = ti & 1;
    if (ti + 1 < nt) {   // DMA next tile into the other buffer
      const u16* sb = X + ((long)(t0 + ti + 1) * 64 + rbase) * 256 + (scg << 3);
      u16* db = &Xs[p ^ 1][0][0] + (w << 9);
#pragma unroll
      for (int r8 = 0; r8 < 8; ++r8) gl2lds16(sb + r8 * 2048, db + r8 * 2048);
    }
    f32x4 acc[4][4];
#pragma unroll
    for (int i = 0; i < 4; ++i)
#pragma unroll
      for (int jj = 0; jj < 4; ++jj) acc[i][jj] = (f32x4){0.f, 0.f, 0.f, 0.f};
#pragma unroll
    for (int kk = 0; kk < 8; ++kk) {
      bf16x8 xf[4];
#pragma unroll
      for (int f = 0; f < 4; ++f)
        xf[f] = *(const bf16x8*)&Xs[p][f * 16 + li][((kk * 4 + g) ^ (li & 7)) << 3];
#pragma unroll
      for (int i = 0; i < 4; ++i)
#pragma unroll
        for (int jj = 0; jj < 4; ++jj)
          acc[i][jj] = (MODE == 0) ? mfma16(xf[i], wf[kk][jj], acc[i][jj])
                                   : mfma16(wf[kk][i], xf[jj], acc[i][jj]);
    }
    asm volatile("s_waitcnt vmcnt(0)" ::: "memory");
    __syncthreads();
    long row0 = (long)(t0 + ti) * 64;
    if (MODE == 0) {
#pragma unroll
      for (int i = 0; i < 4; ++i)
#pragma unroll
        for (int jj = 0; jj < 4; ++jj)
#pragma unroll
          for (int r = 0; r < 4; ++r) {
            int R = i * 16 + g * 4 + r, C = w * 64 + jj * 16 + li;
            out[(row0 + R) * 256 + C] = f2bf(acc[i][jj][r] + bias[C]);
          }
    } else {
      long b = row0 / Nk, rb = row0 - b * Nk;
#pragma unroll
      for (int i = 0; i < 4; ++i)
#pragma unroll
        for (int jj = 0; jj < 4; ++jj)
#pragma unroll
          for (int r = 0; r < 4; ++r) {
            int e = w * 64 + i * 16 + g * 4 + r, xr = jj * 16 + li;
            out[(b * 256 + e) * (long)Nk + rb + xr] = f2bf(acc[i][jj][r] + bias[e]);
          }
    }
  }
}

// One dispatch per layer: Q blocks [0,128), K blocks [128,128+Mkv/2), V rest. 2 tiles/block.
__global__ __launch_bounds__(256, 2) void k_proj(
    const u16* __restrict__ Xq, const u16* __restrict__ Xkv,
    const u16* __restrict__ Wt, const float* __restrict__ beff,
    u16* __restrict__ Qb, u16* __restrict__ Kb, u16* __restrict__ Vt,
    int layer, int Mkv, int Nk) {
  __shared__ __align__(16) u16 Xs[2][64][256];
  int u = blockIdx.x, h = Mkv >> 1;
  if (u < 128)
    proj_body<0>(Xq, Wt + (size_t)layer * 65536, beff + layer * 256, Qb, 0,
                 u * 2, 2, Xs);
  else if (u < 128 + h)
    proj_body<0>(Xkv, Wt + (size_t)(4 + layer) * 65536, beff + (4 + layer) * 256, Kb, 0,
                 (u - 128) * 2, 2, Xs);
  else
    proj_body<1>(Xkv, Wt + (size_t)(8 + layer) * 65536, beff + (8 + layer) * 256, Vt, Nk,
                 (u - 128 - h) * 2, 2, Xs);
}

// ---------------- flash attention v8: 128q block, 2 q-sets/wave, DMA dbuf ----------------
// Grid 256 x 512thr. Block = 128 q-rows, 8 waves: w -> (qt = w>>1 in 0..3, s = w&1).
// Wave: 32 q-rows (2 q-fragment sets) x 32k (s-half of each 64k chunk). K and V LDS
// reads are SHARED across the two q-sets (K is the A-operand, V the B-operand of the
// swapped MFMA) -> LDS bytes per FLOP halved vs v7. K/V staged by global_load_lds
// (pre-swizzled source, linear dest, swizzled read), 128KB double-buffer, 1 barrier/iter.
// Always k-split (ks in {0,1}); writes unnormalized O-partials + row-sums; k_amrg merges.
#define OIX(rq, d) (((rq) << 8) + (((d) + ((rq) << 2)) & 255))
__global__ __launch_bounds__(512, 2) void k_attn2(
    const u16* __restrict__ Qb, const u16* __restrict__ Kb, const u16* __restrict__ Vt,
    const unsigned* __restrict__ Mb,
    float* __restrict__ Op, float* __restrict__ Lg, int Nk) {
  __shared__ __align__(16) char RAW[131584];   // 2 x (K 32KB + V 32KB); epilogue aliases

  int t = threadIdx.x, lane = t & 63, w = t >> 6;
  int qt = w >> 1, s = w & 1;
  int g = lane >> 4, li = lane & 15;
  int sw = li & 7;

  // n: bits 0..3 -> batch (XCD-bijective), 4..6 -> qtile, 7 -> ks
  int n = blockIdx.x;
  int b = ((n & 7) << 1) | ((n >> 3) & 1);
  int q0 = ((n >> 4) & 7) << 7;
  int ks = n >> 7;
  int half = Nk >> 1;
  int W = Nk >> 5, nc = half >> 6;

  const u16* Kg = Kb + (long)b * Nk * 256 + (long)ks * half * 256;
  const u16* Vg = Vt + (long)b * 256 * (long)Nk + ks * half;
  int rowq = b * 1024 + q0 + qt * 32;
  const unsigned* Mg0 = Mb + (long)(rowq + li) * W + ks * (half >> 5);
  const unsigned* Mg1 = Mb + (long)(rowq + 16 + li) * W + ks * (half >> 5);
  const u16* Qg0 = Qb + (long)(rowq + li) * 256 + g * 8;
  const u16* Qg1 = Qb + (long)(rowq + 16 + li) * 256 + g * 8;

  // DMA per-lane pre-swizzled source offsets (K tile [64][256], V tile [256][64])
  int kr0 = (w << 1) | (lane >> 5);                       // 0..15
  long kOff = (long)kr0 * 256 + (((lane & 31) ^ (kr0 & 7)) << 3);
  int vd0 = (w << 3) | (lane >> 3);                       // 0..63
  long vOff = (long)vd0 * Nk + (((lane & 7) ^ (vd0 & 7)) << 3);
  int dOff = w << 9;                                      // wave slot base (u16)

  // ---- prologue: DMA chunk 0 -> buf0; Q frags from global ----
  {
    u16* KB = (u16*)RAW;
    u16* VB = KB + 16384;
#pragma unroll
    for (int c = 0; c < 4; ++c) {
      gl2lds16(Kg + kOff + (long)c * 4096, KB + c * 4096 + dOff);
      gl2lds16(Vg + vOff + (long)c * 64 * Nk, VB + c * 4096 + dOff);
    }
  }
  bf16x8 qf0[8], qf1[8];
#pragma unroll
  for (int kc = 0; kc < 8; ++kc) {
    qf0[kc] = *(const bf16x8*)(Qg0 + kc * 32);
    qf1[kc] = *(const bf16x8*)(Qg1 + kc * 32);
  }
  f32x4 O0[16], O1[16];
#pragma unroll
  for (int dt = 0; dt < 16; ++dt) {
    O0[dt] = (f32x4){0.f, 0.f, 0.f, 0.f};
    O1[dt] = (f32x4){0.f, 0.f, 0.f, 0.f};
  }
  float ls0 = 0.f, ls1 = 0.f;
  asm volatile("s_waitcnt vmcnt(0)" ::: "memory");
  __syncthreads();

  for (int ci = 0; ci < nc; ++ci) {
    int p = ci & 1;
    if (ci + 1 < nc) {   // DMA next chunk into the other buffer (lands under compute)
      const u16* Kc = Kg + (long)(ci + 1) * 64 * 256;
      const u16* Vc = Vg + (long)(ci + 1) * 64;
      u16* KB = (u16*)RAW + (p ^ 1) * 32768;
      u16* VB = KB + 16384;
#pragma unroll
      for (int c = 0; c < 4; ++c) {
        gl2lds16(Kc + kOff + (long)c * 4096, KB + c * 4096 + dOff);
        gl2lds16(Vc + vOff + (long)c * 64 * Nk, VB + c * 4096 + dOff);
      }
    }
    unsigned mw0 = Mg0[(ci << 1) + s];
    unsigned mw1 = Mg1[(ci << 1) + s];
    const u16* Kbuf = (const u16*)RAW + p * 32768;
    const u16* Vbuf = Kbuf + 16384;
    const u16* Kr0 = Kbuf + (s * 32 + li) * 256;
    const u16* Kr1 = Kr0 + 4096;

    // QK^T swapped, K fragments SHARED across both q-sets
    f32x4 sA0 = (f32x4){0.f,0.f,0.f,0.f}, sA1 = (f32x4){0.f,0.f,0.f,0.f};
    f32x4 sB0 = (f32x4){0.f,0.f,0.f,0.f}, sB1 = (f32x4){0.f,0.f,0.f,0.f};
#pragma unroll
    for (int kc = 0; kc < 8; ++kc) {
      int co = ((kc * 4 + g) ^ sw) << 3;
      bf16x8 kf0 = *(const bf16x8*)&Kr0[co];
      bf16x8 kf1 = *(const bf16x8*)&Kr1[co];
      sA0 = mfma16(kf0, qf0[kc], sA0);
      sA1 = mfma16(kf1, qf0[kc], sA1);
      sB0 = mfma16(kf0, qf1[kc], sB0);
      sB1 = mfma16(kf1, qf1[kc], sB1);
    }
    float e00[4], e01[4], e10[4], e11[4];
#pragma unroll
    for (int r = 0; r < 4; ++r) {
      int b0 = g * 4 + r, b1 = 16 + g * 4 + r;
      e00[r] = ((mw0 >> b0) & 1u) ? 0.f : __expf(sA0[r] * 0.0625f);
      e01[r] = ((mw0 >> b1) & 1u) ? 0.f : __expf(sA1[r] * 0.0625f);
      e10[r] = ((mw1 >> b0) & 1u) ? 0.f : __expf(sB0[r] * 0.0625f);
      e11[r] = ((mw1 >> b1) & 1u) ? 0.f : __expf(sB1[r] * 0.0625f);
      ls0 += e00[r] + e01[r];
      ls1 += e10[r] + e11[r];
    }
    int s0l = ((g & 1) << 5) + li;
    bool hi = (g >= 2);
    union { unsigned u[4]; bf16x8 v; } pa0, pa1;
    {
      unsigned u00 = (unsigned)f2bf(e00[0]) | ((unsigned)f2bf(e00[1]) << 16);
      unsigned u01 = (unsigned)f2bf(e00[2]) | ((unsigned)f2bf(e00[3]) << 16);
      unsigned u10 = (unsigned)f2bf(e01[0]) | ((unsigned)f2bf(e01[1]) << 16);
      unsigned u11 = (unsigned)f2bf(e01[2]) | ((unsigned)f2bf(e01[3]) << 16);
      unsigned a0 = __shfl(u00, s0l),      a1 = __shfl(u01, s0l);
      unsigned a2 = __shfl(u00, s0l + 16), a3 = __shfl(u01, s0l + 16);
      unsigned c0 = __shfl(u10, s0l),      c1 = __shfl(u11, s0l);
      unsigned c2 = __shfl(u10, s0l + 16), c3 = __shfl(u11, s0l + 16);
      pa0.u[0] = hi ? c0 : a0; pa0.u[1] = hi ? c1 : a1;
      pa0.u[2] = hi ? c2 : a2; pa0.u[3] = hi ? c3 : a3;
    }
    {
      unsigned u00 = (unsigned)f2bf(e10[0]) | ((unsigned)f2bf(e10[1]) << 16);
      unsigned u01 = (unsigned)f2bf(e10[2]) | ((unsigned)f2bf(e10[3]) << 16);
      unsigned u10 = (unsigned)f2bf(e11[0]) | ((unsigned)f2bf(e11[1]) << 16);
      unsigned u11 = (unsigned)f2bf(e11[2]) | ((unsigned)f2bf(e11[3]) << 16);
      unsigned a0 = __shfl(u00, s0l),      a1 = __shfl(u01, s0l);
      unsigned a2 = __shfl(u00, s0l + 16), a3 = __shfl(u01, s0l + 16);
      unsigned c0 = __shfl(u10, s0l),      c1 = __shfl(u11, s0l);
      unsigned c2 = __shfl(u10, s0l + 16), c3 = __shfl(u11, s0l + 16);
      pa1.u[0] = hi ? c0 : a0; pa1.u[1] = hi ? c1 : a1;
      pa1.u[2] = hi ? c2 : a2; pa1.u[3] = hi ? c3 : a3;
    }
    // PV: V fragments SHARED across both q-sets
    const u16* Vr = Vbuf + li * 64 + (((s * 4 + g) ^ sw) << 3);
#pragma unroll
    for (int dt = 0; dt < 16; ++dt) {
      bf16x8 bv = *(const bf16x8*)&Vr[dt * 1024];
      O0[dt] = mfma16(pa0.v, bv, O0[dt]);
      O1[dt] = mfma16(pa1.v, bv, O1[dt]);
    }
    asm volatile("s_waitcnt vmcnt(0)" ::: "memory");
    __syncthreads();
  }

  // ---- epilogue: in-block s-merge via LDS (aliases dbuf), write partials ----
  float* Om = (float*)RAW;             // 128 x 256 fp32, skewed
  float* Lm = (float*)(RAW + 131072);  // [8][16]
  ls0 += __shfl_xor(ls0, 16); ls0 += __shfl_xor(ls0, 32);
  ls1 += __shfl_xor(ls1, 16); ls1 += __shfl_xor(ls1, 32);
  if (s == 1) {
#pragma unroll
    for (int dt = 0; dt < 16; ++dt)
#pragma unroll
      for (int r = 0; r < 4; ++r) {
        Om[OIX(qt * 32 + g * 4 + r, dt * 16 + li)] = O0[dt][r];
        Om[OIX(qt * 32 + 16 + g * 4 + r, dt * 16 + li)] = O1[dt][r];
      }
    if (g == 0) {
      Lm[(qt * 2) * 16 + li] = ls0;
      Lm[(qt * 2 + 1) * 16 + li] = ls1;
    }
  }
  __syncthreads();
  if (s == 0) {
    float lt0 = ls0 + Lm[(qt * 2) * 16 + li];
    float lt1 = ls1 + Lm[(qt * 2 + 1) * 16 + li];
    if (g == 0) {
      Lg[(long)ks * 16384 + rowq + li] = lt0;
      Lg[(long)ks * 16384 + rowq + 16 + li] = lt1;
    }
    float* Od = Op + ((long)ks * 16384 + rowq) * 256;
#pragma unroll
    for (int dt = 0; dt < 16; ++dt) {
      int d = dt * 16 + li;
#pragma unroll
      for (int r = 0; r < 4; ++r) {
        Od[(g * 4 + r) * 256 + d] = O0[dt][r] + Om[OIX(qt * 32 + g * 4 + r, d)];
        Od[(16 + g * 4 + r) * 256 + d] = O1[dt][r] + Om[OIX(qt * 32 + 16 + g * 4 + r, d)];
      }
    }
  }
}

// ---------------- k-split merge: normalize + LayerNorm + residual ----------------
// Grid 1024 x 256thr. Wave: 4 rows (sub = lane>>4), lane li covers d = j*64+li*4.
__global__ __launch_bounds__(256) void k_amrg(
    const float* __restrict__ Op, const float* __restrict__ Lg,
    const float* __restrict__ gamma, const float* __restrict__ beta,
    const float* __restrict__ rin, float* xres, u16* xbout,
    const float* __restrict__ future, float* __restrict__ dout, int last) {
  int t = threadIdx.x, lane = t & 63, w = t >> 6;
  int sub = lane >> 4, li = lane & 15;
  long row = (long)blockIdx.x * 16 + w * 4 + sub;
  const float* o0 = Op + row * 256;
  const float* o1 = Op + 16384L * 256 + row * 256;
  float rl = 1.f / fmaxf(Lg[row] + Lg[16384 + row], 1e-30f);
  float4 y[4];
  float sm = 0.f, s2 = 0.f;
#pragma unroll
  for (int j = 0; j < 4; ++j) {
    int d0 = j * 64 + li * 4;
    float4 a = *(const float4*)(o0 + d0);
    float4 c = *(const float4*)(o1 + d0);
    float4 yv;
    yv.x = (a.x + c.x) * rl; yv.y = (a.y + c.y) * rl;
    yv.z = (a.z + c.z) * rl; yv.w = (a.w + c.w) * rl;
    y[j] = yv;
    sm += yv.x + yv.y + yv.z + yv.w;
    s2 += yv.x * yv.x + yv.y * yv.y + yv.z * yv.z + yv.w * yv.w;
  }
  sm += __shfl_xor(sm, 1); sm += __shfl_xor(sm, 2);
  sm += __shfl_xor(sm, 4); sm += __shfl_xor(sm, 8);
  s2 += __shfl_xor(s2, 1); s2 += __shfl_xor(s2, 2);
  s2 += __shfl_xor(s2, 4); s2 += __shfl_xor(s2, 8);
  float mu = sm * (1.f / 256.f);
  float rstd = rsqrtf(s2 * (1.f / 256.f) - mu * mu + 1e-5f);
#pragma unroll
  for (int j = 0; j < 4; ++j) {
    int d0 = j * 64 + li * 4;
    float4 g4 = *(const float4*)(gamma + d0);
    float4 b4 = *(const float4*)(beta + d0);
    float4 r4 = *(const float4*)(rin + row * 256 + d0);
    float4 o;
    o.x = (y[j].x - mu) * rstd * g4.x + b4.x + r4.x;
    o.y = (y[j].y - mu) * rstd * g4.y + b4.y + r4.y;
    o.z = (y[j].z - mu) * rstd * g4.z + b4.z + r4.z;
    o.w = (y[j].w - mu) * rstd * g4.w + b4.w + r4.w;
    if (last) {
      float4 f4 = *(const float4*)(future + row * 256 + d0);
      o.x += f4.x; o.y += f4.y; o.z += f4.z; o.w += f4.w;
      *(float4*)(dout + row * 256 + d0) = o;
    } else {
      *(float4*)(xres + row * 256 + d0) = o;
      union { u16 u[4]; uint2 q; } pk;
      pk.u[0] = f2bf(o.x); pk.u[1] = f2bf(o.y);
      pk.u[2] = f2bf(o.z); pk.u[3] = f2bf(o.w);
      *(uint2*)(xbout + row * 256 + d0) = pk.q;
    }
  }
}

// ---------------- fallback flash attention (R7 verified, non-split, 64q) ----------------
__global__ __launch_bounds__(512, 2) void k_attn0(
    const u16* __restrict__ Qb, const u16* __restrict__ Kb, const u16* __restrict__ Vt,
    const unsigned* __restrict__ Mb,
    const float* __restrict__ gamma, const float* __restrict__ beta,
    const float* __restrict__ rin, float* xres, u16* xbout,
    const float* __restrict__ future, float* __restrict__ dout, int last, int Nk) {
  __shared__ __align__(16) char RAW[66816];

  int t = threadIdx.x, lane = t & 63, w = t >> 6;
  int qt = w >> 1, s = w & 1;
  int g = lane >> 4, li = lane & 15;
  int sw = li & 7;

  int n = blockIdx.x;
  int b = ((n & 7) << 1) | ((n >> 3) & 1);
  int q0 = ((n >> 4) & 15) << 6;

  int W = Nk >> 5, nc = Nk >> 6;

  const u16* Kg = Kb + (long)b * Nk * 256;
  const u16* Vg = Vt + (long)b * 256 * (long)Nk;
  const unsigned* Mg = Mb + ((long)b * 1024 + q0 + qt * 16 + li) * W;
  const u16* Qg = Qb + ((long)b * 1024 + q0 + qt * 16 + li) * 256 + g * 8;

  int sA = t, sB = 512 + t, sC = 1024 + t, sD = 1536 + t;
  const u16* KgA = Kg + (long)(sA >> 5) * 256 + (((sA & 31) ^ ((sA >> 5) & 7)) << 3);
  const u16* KgB = Kg + (long)(sB >> 5) * 256 + (((sB & 31) ^ ((sB >> 5) & 7)) << 3);
  const u16* KgC = Kg + (long)(sC >> 5) * 256 + (((sC & 31) ^ ((sC >> 5) & 7)) << 3);
  const u16* KgD = Kg + (long)(sD >> 5) * 256 + (((sD & 31) ^ ((sD >> 5) & 7)) << 3);
  const u16* VgA = Vg + (long)(sA >> 3) * Nk + (((sA & 7) ^ ((sA >> 3) & 7)) << 3);
  const u16* VgB = Vg + (long)(sB >> 3) * Nk + (((sB & 7) ^ ((sB >> 3) & 7)) << 3);
  const u16* VgC = Vg + (long)(sC >> 3) * Nk + (((sC & 7) ^ ((sC >> 3) & 7)) << 3);
  const u16* VgD = Vg + (long)(sD >> 3) * Nk + (((sD & 7) ^ ((sD >> 3) & 7)) << 3);

  u16* Kw = (u16*)RAW;
  u16* Vw = Kw + 16384;

  uint4 k0 = *(const uint4*)KgA, k1 = *(const uint4*)KgB;
  uint4 k2 = *(const uint4*)KgC, k3 = *(const uint4*)KgD;
  uint4 v0 = *(const uint4*)VgA, v1 = *(const uint4*)VgB;
  uint4 v2 = *(const uint4*)VgC, v3 = *(const uint4*)VgD;
  bf16x8 qf[8];
#pragma unroll
  for (int kc = 0; kc < 8; ++kc) qf[kc] = *(const bf16x8*)(Qg + kc * 32);
  *(uint4*)&Kw[sA * 8] = k0; *(uint4*)&Kw[sB * 8] = k1;
  *(uint4*)&Kw[sC * 8] = k2; *(uint4*)&Kw[sD * 8] = k3;
  *(uint4*)&Vw[sA * 8] = v0; *(uint4*)&Vw[sB * 8] = v1;
  *(uint4*)&Vw[sC * 8] = v2; *(uint4*)&Vw[sD * 8] = v3;
  __syncthreads();

  f32x4 O[16];
#pragma unroll
  for (int dt = 0; dt < 16; ++dt) O[dt] = (f32x4){0.f, 0.f, 0.f, 0.f};
  float lsum = 0.f;

  for (int ci = 0; ci < nc; ++ci) {
    long cb2 = (long)((ci + 1 < nc) ? ci + 1 : nc - 1) << 6;
    k0 = *(const uint4*)(KgA + cb2 * 256); k1 = *(const uint4*)(KgB + cb2 * 256);
    k2 = *(const uint4*)(KgC + cb2 * 256); k3 = *(const uint4*)(KgD + cb2 * 256);
    v0 = *(const uint4*)(VgA + cb2);       v1 = *(const uint4*)(VgB + cb2);
    v2 = *(const uint4*)(VgC + cb2);       v3 = *(const uint4*)(VgD + cb2);
    unsigned mw = Mg[(ci << 1) + s];

    const u16* Kr0 = Kw + (s * 32 + li) * 256;
    const u16* Kr1 = Kr0 + 4096;
    f32x4 st0 = (f32x4){0.f, 0.f, 0.f, 0.f}, st1 = (f32x4){0.f, 0.f, 0.f, 0.f};
#pragma unroll
    for (int kc = 0; kc < 8; ++kc) {
      int co = ((kc * 4 + g) ^ sw) << 3;
      st0 = mfma16(*(const bf16x8*)&Kr0[co], qf[kc], st0);
      st1 = mfma16(*(const bf16x8*)&Kr1[co], qf[kc], st1);
    }
    float e0[4], e1[4];
#pragma unroll
    for (int r = 0; r < 4; ++r) {
      bool m0 = (mw >> (g * 4 + r)) & 1u;
      bool m1 = (mw >> (16 + g * 4 + r)) & 1u;
      e0[r] = m0 ? 0.f : __expf(st0[r] * 0.0625f);
      e1[r] = m1 ? 0.f : __expf(st1[r] * 0.0625f);
      lsum += e0[r] + e1[r];
    }
    unsigned u00 = (unsigned)f2bf(e0[0]) | ((unsigned)f2bf(e0[1]) << 16);
    unsigned u01 = (unsigned)f2bf(e0[2]) | ((unsigned)f2bf(e0[3]) << 16);
    unsigned u10 = (unsigned)f2bf(e1[0]) | ((unsigned)f2bf(e1[1]) << 16);
    unsigned u11 = (unsigned)f2bf(e1[2]) | ((unsigned)f2bf(e1[3]) << 16);
    int s0l = ((g & 1) << 5) + li;
    unsigned a0 = __shfl(u00, s0l),      a1 = __shfl(u01, s0l);
    unsigned a2 = __shfl(u00, s0l + 16), a3 = __shfl(u01, s0l + 16);
    unsigned c0 = __shfl(u10, s0l),      c1 = __shfl(u11, s0l);
    unsigned c2 = __shfl(u10, s0l + 16), c3 = __shfl(u11, s0l + 16);
    union { unsigned u[4]; bf16x8 v; } pa;
    bool hi = (g >= 2);
    pa.u[0] = hi ? c0 : a0; pa.u[1] = hi ? c1 : a1;
    pa.u[2] = hi ? c2 : a2; pa.u[3] = hi ? c3 : a3;
    const u16* Vr = Vw + li * 64 + (((s * 4 + g) ^ sw) << 3);
#pragma unroll
    for (int dt = 0; dt < 16; ++dt) {
      bf16x8 bv = *(const bf16x8*)&Vr[dt * 1024];
      O[dt] = mfma16(pa.v, bv, O[dt]);
    }
    __syncthreads();
    if (ci + 1 < nc) {
      *(uint4*)&Kw[sA * 8] = k0; *(uint4*)&Kw[sB * 8] = k1;
      *(uint4*)&Kw[sC * 8] = k2; *(uint4*)&Kw[sD * 8] = k3;
      *(uint4*)&Vw[sA * 8] = v0; *(uint4*)&Vw[sB * 8] = v1;
      *(uint4*)&Vw[sC * 8] = v2; *(uint4*)&Vw[sD * 8] = v3;
      __syncthreads();
    }
  }

  float* Om = (float*)RAW;
  float* Lm = (float*)(RAW + 66560);
  lsum += __shfl_xor(lsum, 16);
  lsum += __shfl_xor(lsum, 32);
  if (s == 1) {
#pragma unroll
    for (int dt = 0; dt < 16; ++dt)
#pragma unroll
      for (int r = 0; r < 4; ++r)
        Om[(qt * 16 + g * 4 + r) * 260 + dt * 16 + li] = O[dt][r];
    if (g == 0) Lm[qt * 16 + li] = lsum;
  }
  __syncthreads();
  if (s == 0) {
    float ltot = lsum + Lm[qt * 16 + li];
#pragma unroll
    for (int dt = 0; dt < 16; ++dt)
#pragma unroll
      for (int r = 0; r < 4; ++r)
        O[dt][r] += Om[(qt * 16 + g * 4 + r) * 260 + dt * 16 + li];
    float rl = 1.f / fmaxf(ltot, 1e-30f);
    float rq[4];
#pragma unroll
    for (int r = 0; r < 4; ++r) rq[r] = __shfl(rl, g * 4 + r);
    float sm[4] = {0.f, 0.f, 0.f, 0.f}, s2[4] = {0.f, 0.f, 0.f, 0.f};
#pragma unroll
    for (int dt = 0; dt < 16; ++dt)
#pragma unroll
      for (int r = 0; r < 4; ++r) {
        float y = O[dt][r] * rq[r];
        O[dt][r] = y;
        sm[r] += y; s2[r] += y * y;
      }
#pragma unroll
    for (int r = 0; r < 4; ++r) {
      float a = sm[r], c = s2[r];
      a += __shfl_xor(a, 1); a += __shfl_xor(a, 2);
      a += __shfl_xor(a, 4); a += __shfl_xor(a, 8);
      c += __shfl_xor(c, 1); c += __shfl_xor(c, 2);
      c += __shfl_xor(c, 4); c += __shfl_xor(c, 8);
      float m = a * (1.f / 256.f);
      sm[r] = m;
      s2[r] = rsqrtf(c * (1.f / 256.f) - m * m + 1e-5f);
    }
#pragma unroll
    for (int dt = 0; dt < 16; ++dt) {
      int d = dt * 16 + li;
      float gm = gamma[d], bt = beta[d];
#pragma unroll
      for (int r = 0; r < 4; ++r) {
        int q = q0 + qt * 16 + g * 4 + r;
        long idx = ((long)b * 1024 + q) * 256 + d;
        float o = (O[dt][r] - sm[r]) * s2[r] * gm + bt + rin[idx];
        if (last) dout[idx] = o + future[idx];
        else { xres[idx] = o; xbout[idx] = f2bf(o); }
      }
    }
  }
}

// ---------------- host ----------------
extern "C" void kernel_launch(void* const* d_in, const int* in_sizes, int n_in,
                              void* d_out, int out_size, void* d_ws, size_t ws_size,
                              hipStream_t stream) {
  const float* future  = (const float*)d_in[0];
  const float* history = (const float*)d_in[1];
  const float* graph   = (const float*)d_in[2];
  const void*  mask_hf = d_in[3];
  const void*  mask_fg = d_in[4];
  const float* Wq = (const float*)d_in[5];
  const float* bq = (const float*)d_in[6];
  const float* Wk = (const float*)d_in[7];
  const float* bk = (const float*)d_in[8];
  const float* Wv = (const float*)d_in[9];
  const float* bv = (const float*)d_in[10];
  const float* gamma = (const float*)d_in[11];
  const float* beta  = (const float*)d_in[12];
  float* dout = (float*)d_out;

  char* ws = (char*)d_ws;
  size_t off = 0;
  int* flag = (int*)(ws + off); off += 256;
  u16* Wt = (u16*)(ws + off);  off += (size_t)12 * 65536 * 2;
  float* T = (float*)(ws + off); off += (size_t)12 * 65536 * 4;
  float* beff = (float*)(ws + off); off += (size_t)12 * 256 * 4;
  u16* xb = (u16*)(ws + off);  off += (size_t)16384 * 256 * 2;
  float* x = (float*)(ws + off); off += (size_t)16384 * 256 * 4;
  u16* hb = (u16*)(ws + off);  off += (size_t)16384 * 256 * 2;
  u16* gb = (u16*)(ws + off);  off += (size_t)32768 * 256 * 2;
  u16* Qb = (u16*)(ws + off);  off += (size_t)16384 * 256 * 2;
  u16* Kb = (u16*)(ws + off);  off += (size_t)32768 * 256 * 2;
  u16* Vtb = (u16*)(ws + off); off += (size_t)32768 * 256 * 2;
  unsigned* Mbhf = (unsigned*)(ws + off); off += (size_t)16 * 1024 * 1024 / 8;
  unsigned* Mbfg = (unsigned*)(ws + off); off += (size_t)16 * 1024 * 2048 / 8;
  if (ws_size < off) return;
  float* Op = (float*)(ws + off); off += (size_t)2 * 16384 * 256 * 4;
  float* Lg = (float*)(ws + off); off += (size_t)2 * 16384 * 4;
  int split = (ws_size >= off) ? 1 : 0;

  k_flag<<<1, 64, 0, stream>>>((const unsigned char*)mask_hf, flag);
  k_pack<<<8192, 256, 0, stream>>>(mask_hf, flag, Mbhf);
  k_pack<<<16384, 256, 0, stream>>>(mask_fg, flag, Mbfg);
  k_wc1<<<dim3(256, 12), 256, 0, stream>>>(Wq, Wk, Wv, T);
  k_wc2<<<dim3(16, 12), 256, 0, stream>>>(Wq, Wk, Wv, T, Wt);
  k_bc<<<12, 256, 0, stream>>>(Wq, Wk, Wv, bq, bk, bv, beff);
  k_cvt3<<<16384, 256, 0, stream>>>(future, history, graph, xb, hb, gb);

  for (int i = 0; i < 4; ++i) {
    const u16* src = (i < 2) ? hb : gb;
    int Mkv = (i < 2) ? 256 : 512;
    int Nk = (i < 2) ? 1024 : 2048;
    const unsigned* mb = (i < 2) ? Mbhf : Mbfg;
    const float* rin = (i == 0) ? future : x;
    int last = (i == 3) ? 1 : 0;
    k_proj<<<128 + Mkv, 256, 0, stream>>>(xb, src, Wt, beff, Qb, Kb, Vtb, i, Mkv, Nk);
    if (split) {
      k_attn2<<<256, 512, 0, stream>>>(Qb, Kb, Vtb, mb, Op, Lg, Nk);
      k_amrg<<<1024, 256, 0, stream>>>(Op, Lg, gamma + i * 256, beta + i * 256,
                                       rin, x, xb, future, dout, last);
    } else {
      k_attn0<<<256, 512, 0, stream>>>(Qb, Kb, Vtb, mb, gamma + i * 256, beta + i * 256,
                                       rin, x, xb, future, dout, last, Nk);
    }
  }
}